// Round 5
// baseline (585.007 us; speedup 1.0000x reference)
//
#include <hip/hip_runtime.h>
#include <math.h>
#include <stddef.h>

#define B_ 2
#define N_ 2048
#define DM 2048
#define H_ 16
#define HD 128
#define INNER 2048
#define TRIPLE 6144
#define M_ (B_ * N_)   // 4096
#define T_ 32          // chunk length
#define NCHK (N_ / T_) // 64 chunks

typedef __bf16 bf16x8 __attribute__((ext_vector_type(8)));
typedef float  f32x4v __attribute__((ext_vector_type(4)));
typedef __attribute__((address_space(1))) const void gvoid;
typedef __attribute__((address_space(3))) void lvoid;

__device__ __forceinline__ float sig_(float x) { return 1.0f / (1.0f + __expf(-x)); }

__device__ __forceinline__ unsigned short f2bf(float f) {
    unsigned u = __float_as_uint(f);
    u += 0x7FFFu + ((u >> 16) & 1u);     // RNE
    return (unsigned short)(u >> 16);
}
__device__ __forceinline__ float bf2f(unsigned short h) {
    return __uint_as_float((unsigned)h << 16);
}
__device__ __forceinline__ void unpack8(uint4 r, float* f) {
    f[0] = __uint_as_float(r.x << 16); f[1] = __uint_as_float(r.x & 0xffff0000u);
    f[2] = __uint_as_float(r.y << 16); f[3] = __uint_as_float(r.y & 0xffff0000u);
    f[4] = __uint_as_float(r.z << 16); f[5] = __uint_as_float(r.z & 0xffff0000u);
    f[6] = __uint_as_float(r.w << 16); f[7] = __uint_as_float(r.w & 0xffff0000u);
}

// Workgroup barrier that waits ONLY on LDS ops (lgkmcnt(0)); prefetched
// global loads stay in flight across it.
__device__ __forceinline__ void lds_barrier() {
    asm volatile("" ::: "memory");
    __builtin_amdgcn_s_waitcnt(0xC07F);
    __builtin_amdgcn_s_barrier();
    asm volatile("" ::: "memory");
}

// Raw barrier: NO waitcnt drain (counted-vmcnt pipeline crosses it).
__device__ __forceinline__ void bar() {
    asm volatile("" ::: "memory");
    __builtin_amdgcn_s_barrier();
    asm volatile("" ::: "memory");
}

__global__ __launch_bounds__(256) void cast_bf16(
    const float* __restrict__ in, unsigned short* __restrict__ out, int n)
{
    int i = (blockIdx.x * 256 + threadIdx.x) * 4;
    if (i < n) {
        float4 v = *(const float4*)(in + i);
        out[i + 0] = f2bf(v.x); out[i + 1] = f2bf(v.y);
        out[i + 2] = f2bf(v.z); out[i + 3] = f2bf(v.w);
    }
}

// Cast [W_qkv ; W_g] (8192 x 2048 fp32, two sources) into 16x32-TILED bf16:
// packed elem addr(n,k) = ((n>>4)*64 + (k>>5))*512 + (n&15)*32 + (k&31).
// A wave's MFMA B-fragment load then reads one contiguous 1KB block with
// per-lane offset lr*32 + kg*8 (fully coalesced, values identical to the
// old LDS-staged path).
__global__ __launch_bounds__(256) void pack_cast_w(
    const float* __restrict__ Wq, const float* __restrict__ Wg,
    unsigned short* __restrict__ dst)
{
    const int i = blockIdx.x * 256 + threadIdx.x;   // one 8-elem chunk each
    const int e = i * 8;
    const int n = e >> 11;            // row 0..8191
    const int k = e & 2047;
    const float* src = (n < TRIPLE) ? (Wq + (size_t)n * DM + k)
                                    : (Wg + (size_t)(n - TRIPLE) * DM + k);
    float4 v0 = *(const float4*)(src);
    float4 v1 = *(const float4*)(src + 4);
    ushort4 u0, u1;
    u0.x = f2bf(v0.x); u0.y = f2bf(v0.y); u0.z = f2bf(v0.z); u0.w = f2bf(v0.w);
    u1.x = f2bf(v1.x); u1.y = f2bf(v1.y); u1.z = f2bf(v1.z); u1.w = f2bf(v1.w);
    const size_t off = ((size_t)((n >> 4) * 64 + (k >> 5)) << 9) + (n & 15) * 32 + (k & 31);
    *(ushort4*)(dst + off)     = u0;
    *(ushort4*)(dst + off + 4) = u1;
}

// hi/lo split cast: hi = RNE-bf16(x), lo = bf16(x - hi)
__global__ __launch_bounds__(256) void cast_hilo(
    const float* __restrict__ in, unsigned short* __restrict__ hi,
    unsigned short* __restrict__ lo, int n)
{
    int i = (blockIdx.x * 256 + threadIdx.x) * 4;
    if (i < n) {
        float4 v = *(const float4*)(in + i);
        ushort4 h, l;
        h.x = f2bf(v.x); l.x = f2bf(v.x - bf2f(h.x));
        h.y = f2bf(v.y); l.y = f2bf(v.y - bf2f(h.y));
        h.z = f2bf(v.z); l.z = f2bf(v.z - bf2f(h.z));
        h.w = f2bf(v.w); l.w = f2bf(v.w - bf2f(h.w));
        *(ushort4*)(hi + i) = h;
        *(ushort4*)(lo + i) = l;
    }
}

// ============================================================================
// Fused (qkv | g) GEMM, 256x256 tile, R5 structure: A in LDS (dbuf 64 KiB),
// B REGISTER-DIRECT from 16x32-tiled packed weights (L2-resident).
// Rationale: R2-R4 plateaued ~138us because per-CU LDS traffic (A 128KB +
// B 64KB reads + 64KB gll writes = 256KB = ~2000cyc @128B/cyc) nearly fills
// the 2509-cyc MFMA window. Moving B to coalesced global loads cuts LDS to
// 160KB/tile and simplifies sync to 2 barriers/tile.
//  Per-tile body: RD aF(8 ds) | issue B(kt+1) 8 vmem | q00 q01 | RD aG(8 ds)
//   | q11 q10 (lgkm waits drain aG) | bar1 | STAGE A(kt+2)->buf[kt&1] (4 gll)
//   | vmcnt(12) retires A(kt+1) | bar2.
//  FIFO vmem ledger (order pinned by memory-clobber asm at bar/vmcnt):
//   issue order per tile = B(kt+1)x8 then A(kt+2)x4. At boundary outstanding =
//   [A(kt+1)4, B(kt+1)8, A(kt+2)4]=16 -> vmcnt(12) retires exactly A(kt+1).
//   kt==KT-2: no stage -> vmcnt(8). B-reg loads are compiler-tracked (precise
//   per-use waits; FIFO means they never over-drain the staging loads).
//  B values per lane identical to the old LDS path -> bitwise-same MFMA.
// ============================================================================
__global__ __launch_bounds__(512) void gemm_fused256(
    const unsigned short* __restrict__ A, const unsigned short* __restrict__ Bp,
    unsigned short* __restrict__ outQ, float* __restrict__ outG,
    int M, int NQ, int NG, int K)
{
    __shared__ unsigned short As[2][256 * 64];   // 64 KiB total

    const int tid = threadIdx.x;
    const int w   = tid >> 6;       // 0..7
    const int l   = tid & 63;
    const int wm  = w >> 2;         // 0..1 (M)
    const int wn  = w & 3;          // 0..3 (N)
    const int lr  = l & 15;
    const int kg  = l >> 4;         // 0..3

    // XCD-aware bijective swizzle (512 blocks, 512 % 8 == 0)
    const int bid = blockIdx.x;
    const int swz = (bid & 7) * 64 + (bid >> 3);
    const int by  = swz & 15;       // 16 row-tiles
    const int bx  = swz >> 4;       // 32 col-tiles
    const int row0 = by * 256;
    const int col0 = bx * 256;

    // ---- A staging: LDS linear dest, pre-swizzled global source ----
    const int srow = w * 8 + (l >> 3);           // 0..63
    const int schk = ((l & 7) ^ (l >> 3)) * 8;
    const unsigned short* Ath = A + (size_t)(row0 + srow) * K + schk;

    // ---- A fragment reads (swizzled) ----
    const int fsw0 = ((0 + kg) ^ (lr & 7)) * 8;
    const int fsw1 = ((4 + kg) ^ (lr & 7)) * 8;
    const int arb  = wm * 64 + lr;

    // ---- B packed addressing ----
    // col = col0 + nh*128 + wn*32 + n_*16  ->  nb = col>>4
    // lane ptr = Bp + (nb*64 + kc)*512 + lr*32 + kg*8,  kc = kt*2 + ks
    const unsigned short* Bl0 = Bp + lr * 32 + kg * 8;
    int nbOff[2][2];
#pragma unroll
    for (int nh_ = 0; nh_ < 2; ++nh_)
#pragma unroll
        for (int n_ = 0; n_ < 2; ++n_)
            nbOff[nh_][n_] = (((col0 >> 4) + nh_ * 8 + wn * 2 + n_) << 15); // *64*512

    f32x4v acc[2][2][4][2];
#pragma unroll
    for (int a0 = 0; a0 < 2; ++a0)
#pragma unroll
        for (int a1 = 0; a1 < 2; ++a1)
#pragma unroll
            for (int a2 = 0; a2 < 4; ++a2)
#pragma unroll
                for (int a3 = 0; a3 < 2; ++a3)
                    acc[a0][a1][a2][a3] = (f32x4v){0.f, 0.f, 0.f, 0.f};

#define STAGE_T(buf, kt) do {                                                    \
        _Pragma("unroll")                                                        \
        for (int p_ = 0; p_ < 4; ++p_) {                                         \
            const unsigned short* g_ = Ath + (size_t)(p_ * 64) * K + (kt) * 64;  \
            unsigned short* d_ = &As[buf][(p_ * 64 + w * 8) * 64];               \
            __builtin_amdgcn_global_load_lds((gvoid*)g_, (lvoid*)d_, 16, 0, 0);  \
        }                                                                        \
    } while (0)

#define LOAD_B(DST, kt) do {                                                     \
        _Pragma("unroll")                                                        \
        for (int nh_ = 0; nh_ < 2; ++nh_)                                        \
        _Pragma("unroll")                                                        \
        for (int n_ = 0; n_ < 2; ++n_)                                           \
        _Pragma("unroll")                                                        \
        for (int ks_ = 0; ks_ < 2; ++ks_)                                        \
            DST[nh_][n_][ks_] = *(const bf16x8*)(                                \
                Bl0 + nbOff[nh_][n_] + ((kt) * 2 + ks_) * 512);                  \
    } while (0)

#define RD_A(DST, BASE, HOFF)                                        \
    _Pragma("unroll")                                                \
    for (int m_ = 0; m_ < 4; ++m_) {                                 \
        const int r_ = ((HOFF) + arb + m_ * 16) * 64;                \
        DST[m_][0] = *(const bf16x8*)((BASE) + r_ + fsw0);           \
        DST[m_][1] = *(const bf16x8*)((BASE) + r_ + fsw1);           \
    }

#define Q_MFMA(MH, NH, AF, BB)                                               \
    __builtin_amdgcn_s_setprio(1);                                           \
    _Pragma("unroll")                                                        \
    for (int m_ = 0; m_ < 4; ++m_)                                           \
        _Pragma("unroll")                                                    \
        for (int n_ = 0; n_ < 2; ++n_) {                                     \
            acc[MH][NH][m_][n_] = __builtin_amdgcn_mfma_f32_16x16x32_bf16(   \
                AF[m_][0], BB[NH][n_][0], acc[MH][NH][m_][n_], 0, 0, 0);     \
            acc[MH][NH][m_][n_] = __builtin_amdgcn_mfma_f32_16x16x32_bf16(   \
                AF[m_][1], BB[NH][n_][1], acc[MH][NH][m_][n_], 0, 0, 0);     \
        }                                                                    \
    __builtin_amdgcn_s_setprio(0);

    const int KT = K >> 6;   // 32 (even)

    bf16x8 aF[4][2], aG[4][2];
    bf16x8 bX[2][2][2], bY[2][2][2];   // B ping-pong: [nh][n][ks]

    // Prologue: stage A tile0 + tile1 (8 gll), load B tile0 (8 vmem regs).
    STAGE_T(0, 0);
    STAGE_T(1, 1);
    LOAD_B(bX, 0);
    asm volatile("s_waitcnt vmcnt(12)" ::: "memory");   // A tile0 landed
    bar();

#define TILE_BODY(kt, BCUR, BNXT) do {                                          \
        const unsigned short* Ab = As[(kt) & 1];                                \
        RD_A(aF, Ab, 0);                                                        \
        if ((kt) + 1 < KT) LOAD_B(BNXT, (kt) + 1);                              \
        Q_MFMA(0, 0, aF, BCUR);                                                 \
        Q_MFMA(0, 1, aF, BCUR);                                                 \
        RD_A(aG, Ab, 128);                                                      \
        Q_MFMA(1, 1, aG, BCUR);                                                 \
        Q_MFMA(1, 0, aG, BCUR);                                                 \
        if ((kt) + 2 < KT) {                                                    \
            bar();                      /* all waves drained buf[kt&1] */       \
            STAGE_T((kt) & 1, (kt) + 2);                                        \
        }                                                                       \
        if ((kt) + 1 < KT) {                                                    \
            if ((kt) < KT - 2) { asm volatile("s_waitcnt vmcnt(12)" ::: "memory"); } \
            else               { asm volatile("s_waitcnt vmcnt(8)"  ::: "memory"); } \
            bar();                      /* A(kt+1) visible to all */            \
        }                                                                       \
    } while (0)

    // Q_MFMA's BB arg indexes [NH]: pass the whole ping-pong array.
    for (int kt = 0; kt < KT; kt += 2) {
        TILE_BODY(kt,     bX, bY);
        TILE_BODY(kt + 1, bY, bX);
    }
#undef TILE_BODY
#undef STAGE_T
#undef LOAD_B
#undef RD_A
#undef Q_MFMA

    // -------- epilogue --------
    const bool isG = (col0 >= NQ);   // block-uniform (NQ = 6144 = 24*256)
#pragma unroll
    for (int mh = 0; mh < 2; ++mh)
#pragma unroll
    for (int m = 0; m < 4; ++m) {
        const int rbase = row0 + mh * 128 + wm * 64 + m * 16 + kg * 4;
#pragma unroll
        for (int nh = 0; nh < 2; ++nh)
#pragma unroll
        for (int n = 0; n < 2; ++n) {
            const int c = col0 + nh * 128 + wn * 32 + n * 16 + lr;
#pragma unroll
            for (int j = 0; j < 4; ++j) {
                float v = acc[mh][nh][m][n][j];
                const size_t r = (size_t)(rbase + j);
                if (!isG) {
                    outQ[r * NQ + c] = f2bf(v);
                } else {
                    v = v * sig_(v);
                    outG[r * NG + (c - NQ)] = v;
                }
            }
        }
    }
}

// ============================================================================
// W_o projection GEMM (fp32 out): 128x128 tile, BK=64, double-buffered LDS
// (64 KiB -> 2 blocks/CU), counted vmcnt(8), 2 barriers/tile, XOR swizzle,
// XCD swizzle. (R4 kernel, unchanged.)
// ============================================================================
__global__ __launch_bounds__(256) void gemm_bf16f(
    const unsigned short* __restrict__ A, const unsigned short* __restrict__ Bw,
    float* __restrict__ C, int M, int N, int K)
{
    __shared__ unsigned short As[2][128 * 64];
    __shared__ unsigned short Bs[2][128 * 64];

    const int tid = threadIdx.x;
    const int w   = tid >> 6;      // 0..3
    const int l   = tid & 63;
    const int wm  = w >> 1;        // 0..1
    const int wn  = w & 1;         // 0..1
    const int lr  = l & 15;
    const int kg  = l >> 4;        // 0..3

    const int bid = blockIdx.x;
    const int swz = (bid & 7) * 64 + (bid >> 3);
    const int by  = swz & 31;      // 32 row-tiles (M=4096)
    const int bx  = swz >> 5;      // 16 col-tiles (N=2048)
    const int row0 = by * 128;
    const int col0 = bx * 128;

    const int srow = w * 8 + (l >> 3);           // 0..31
    const int schk = ((l & 7) ^ (l >> 3)) * 8;
    const unsigned short* Ath = A  + (size_t)(row0 + srow) * K + schk;
    const unsigned short* Bth = Bw + (size_t)(col0 + srow) * K + schk;

    const int fsw0 = ((0 + kg) ^ (lr & 7)) * 8;
    const int fsw1 = ((4 + kg) ^ (lr & 7)) * 8;
    const int arb  = wm * 64 + lr;
    const int brb  = wn * 64 + lr;

    f32x4v acc[4][4];
#pragma unroll
    for (int i = 0; i < 4; ++i)
#pragma unroll
        for (int j = 0; j < 4; ++j) acc[i][j] = (f32x4v){0.f, 0.f, 0.f, 0.f};

#define STAGE_T(buf, kt) do {                                                    \
        _Pragma("unroll")                                                        \
        for (int p_ = 0; p_ < 4; ++p_) {                                         \
            const unsigned short* ga_ = Ath + (size_t)(p_ * 32) * K + (kt) * 64; \
            const unsigned short* gb_ = Bth + (size_t)(p_ * 32) * K + (kt) * 64; \
            unsigned short* da_ = &As[buf][(p_ * 32 + w * 8) * 64];              \
            unsigned short* db_ = &Bs[buf][(p_ * 32 + w * 8) * 64];              \
            __builtin_amdgcn_global_load_lds((gvoid*)ga_, (lvoid*)da_, 16, 0, 0);\
            __builtin_amdgcn_global_load_lds((gvoid*)gb_, (lvoid*)db_, 16, 0, 0);\
        }                                                                        \
    } while (0)

    const int KT = K >> 6;   // 32

    STAGE_T(0, 0);
    STAGE_T(1, 1);
    asm volatile("s_waitcnt vmcnt(8)" ::: "memory");
    bar();

    bf16x8 aF[4][2], bF[4][2];

#pragma unroll 2
    for (int kt = 0; kt < KT; ++kt) {
        const unsigned short* Ab = As[kt & 1];
        const unsigned short* Bb = Bs[kt & 1];

#pragma unroll
        for (int m_ = 0; m_ < 4; ++m_) {
            const int r_ = (arb + m_ * 16) * 64;
            aF[m_][0] = *(const bf16x8*)(Ab + r_ + fsw0);
            aF[m_][1] = *(const bf16x8*)(Ab + r_ + fsw1);
        }
#pragma unroll
        for (int n_ = 0; n_ < 4; ++n_) {
            const int r_ = (brb + n_ * 16) * 64;
            bF[n_][0] = *(const bf16x8*)(Bb + r_ + fsw0);
            bF[n_][1] = *(const bf16x8*)(Bb + r_ + fsw1);
        }
        bar();                                    // all reads of buf cur done

        if (kt + 2 < KT) STAGE_T(kt & 1, kt + 2);

        __builtin_amdgcn_s_setprio(1);
#pragma unroll
        for (int ks = 0; ks < 2; ++ks)
#pragma unroll
            for (int m_ = 0; m_ < 4; ++m_)
#pragma unroll
                for (int n_ = 0; n_ < 4; ++n_)
                    acc[m_][n_] = __builtin_amdgcn_mfma_f32_16x16x32_bf16(
                        aF[m_][ks], bF[n_][ks], acc[m_][n_], 0, 0, 0);
        __builtin_amdgcn_s_setprio(0);

        if (kt < KT - 2) {
            asm volatile("s_waitcnt vmcnt(8)" ::: "memory");
        } else if (kt == KT - 2) {
            asm volatile("s_waitcnt vmcnt(0)" ::: "memory");
        }
        bar();
    }
#undef STAGE_T

#pragma unroll
    for (int m_ = 0; m_ < 4; ++m_)
#pragma unroll
        for (int j = 0; j < 4; ++j) {
            const int r = row0 + wm * 64 + m_ * 16 + kg * 4 + j;
#pragma unroll
            for (int n_ = 0; n_ < 4; ++n_) {
                const int c = col0 + wn * 64 + n_ * 16 + lr;
                C[(size_t)r * N + c] = acc[m_][n_][j];
            }
        }
}

// ab = sigmoid(x @ W_ab^T + b_ab) via split-bf16 MFMA (fp32-grade).
// 256 blocks x 16 rows; 4 waves split K 4-ways, LDS reduce.
__global__ __launch_bounds__(256) void gemm_ab(
    const unsigned short* __restrict__ xhi, const unsigned short* __restrict__ xlo,
    const unsigned short* __restrict__ wh, const unsigned short* __restrict__ wl,
    const float* __restrict__ b_ab, float* __restrict__ absig)
{
    __shared__ float sums[4][16][32];
    const int tid = threadIdx.x;
    const int w = tid >> 6, lane = tid & 63;
    const int lr = lane & 15, lk8 = (lane >> 4) * 8, lrow4 = (lane >> 4) * 4;
    const int row = blockIdx.x * 16 + lr;
    const int kw  = w * (DM / 4);    // per-wave K-chunk base

    f32x4v acc[2];
    acc[0] = (f32x4v){0.f,0.f,0.f,0.f};
    acc[1] = (f32x4v){0.f,0.f,0.f,0.f};
    const unsigned short* Ah = xhi + (size_t)row * DM + kw;
    const unsigned short* Al = xlo + (size_t)row * DM + kw;

    for (int k0 = 0; k0 < DM / 4; k0 += 32) {
        bf16x8 ah = *(const bf16x8*)(Ah + k0 + lk8);
        bf16x8 al = *(const bf16x8*)(Al + k0 + lk8);
#pragma unroll
        for (int nt = 0; nt < 2; ++nt) {
            bf16x8 whf = *(const bf16x8*)(wh + (size_t)(nt * 16 + lr) * DM + kw + k0 + lk8);
            bf16x8 wlf = *(const bf16x8*)(wl + (size_t)(nt * 16 + lr) * DM + kw + k0 + lk8);
            acc[nt] = __builtin_amdgcn_mfma_f32_16x16x32_bf16(ah, whf, acc[nt], 0, 0, 0);
            acc[nt] = __builtin_amdgcn_mfma_f32_16x16x32_bf16(ah, wlf, acc[nt], 0, 0, 0);
            acc[nt] = __builtin_amdgcn_mfma_f32_16x16x32_bf16(al, whf, acc[nt], 0, 0, 0);
        }
    }

#pragma unroll
    for (int nt = 0; nt < 2; ++nt)
#pragma unroll
        for (int j = 0; j < 4; ++j)
            sums[w][lrow4 + j][nt * 16 + lr] = acc[nt][j];
    __syncthreads();

    for (int e = tid; e < 512; e += 256) {
        const int r = e >> 5, c = e & 31;
        float s = sums[0][r][c] + sums[1][r][c] + sums[2][r][c] + sums[3][r][c];
        absig[(size_t)(blockIdx.x * 16 + r) * 32 + c] = sig_(s + b_ab[c]);
    }
}

// conv(K=4, causal, depthwise) + silu + per-head l2norm of q,k.
// Vectorized bf16x8 IO; fp32 accumulation and norm.
__global__ __launch_bounds__(256) void conv_silu_norm(
    const unsigned short* __restrict__ qkv, const float* __restrict__ conv_w,
    unsigned short* __restrict__ outb)
{
    __shared__ float buf[TRIPLE];
    __shared__ float scales[32];
    const int bn = blockIdx.x;
    const int n = bn & (N_ - 1);
    const int tid = threadIdx.x;
    const unsigned short* base = qkv + (size_t)bn * TRIPLE;

#pragma unroll
    for (int it = 0; it < 3; ++it) {
        const int c8 = (tid + it * 256) * 8;
        float cw[32];
#pragma unroll
        for (int q4 = 0; q4 < 8; ++q4)
            *(float4*)&cw[q4 * 4] = *(const float4*)(conv_w + (size_t)c8 * 4 + q4 * 4);
        float acc[8] = {0.f,0.f,0.f,0.f,0.f,0.f,0.f,0.f};
#pragma unroll
        for (int j = 0; j < 4; ++j) {
            if (n - 3 + j >= 0) {
                uint4 r = *(const uint4*)(base + (ptrdiff_t)(j - 3) * TRIPLE + c8);
                float xf[8]; unpack8(r, xf);
#pragma unroll
                for (int e = 0; e < 8; ++e) acc[e] += xf[e] * cw[e * 4 + j];
            }
        }
        float4 o0, o1;
        o0.x = acc[0] * sig_(acc[0]); o0.y = acc[1] * sig_(acc[1]);
        o0.z = acc[2] * sig_(acc[2]); o0.w = acc[3] * sig_(acc[3]);
        o1.x = acc[4] * sig_(acc[4]); o1.y = acc[5] * sig_(acc[5]);
        o1.z = acc[6] * sig_(acc[6]); o1.w = acc[7] * sig_(acc[7]);
        *(float4*)&buf[c8] = o0;
        *(float4*)&buf[c8 + 4] = o1;
    }
    __syncthreads();

    const int g = tid >> 3, l = tid & 7;
    {
        int off = (g < 16) ? g * HD : 2048 + (g - 16) * HD;
        float s = 0.f;
        for (int i = l; i < HD; i += 8) { float v = buf[off + i]; s += v * v; }
        s += __shfl_xor(s, 1); s += __shfl_xor(s, 2); s += __shfl_xor(s, 4);
        if (l == 0) scales[g] = 1.0f / fmaxf(sqrtf(s), 1e-12f);
    }
    __syncthreads();

    unsigned short* ob = outb + (size_t)bn * TRIPLE;
#pragma unroll
    for (int it = 0; it < 3; ++it) {
        const int c8 = (tid + it * 256) * 8;
        float sc = 1.f;
        if (c8 < 2048) sc = scales[c8 >> 7];
        else if (c8 < 4096) sc = scales[16 + ((c8 - 2048) >> 7)];
        float4 f0 = *(const float4*)&buf[c8];
        float4 f1 = *(const float4*)&buf[c8 + 4];
        ushort4 u0, u1;
        u0.x = f2bf(f0.x * sc); u0.y = f2bf(f0.y * sc);
        u0.z = f2bf(f0.z * sc); u0.w = f2bf(f0.w * sc);
        u1.x = f2bf(f1.x * sc); u1.y = f2bf(f1.y * sc);
        u1.z = f2bf(f1.z * sc); u1.w = f2bf(f1.w * sc);
        *(ushort4*)(ob + c8) = u0;
        *(ushort4*)(ob + c8 + 4) = u1;
    }
}

// ---------------- chunked delta rule ----------------
__global__ __launch_bounds__(256) void chunk_prep(
    const unsigned short* __restrict__ qkvc, const float* __restrict__ absig,
    float* __restrict__ Ubar, unsigned short* __restrict__ What,
    unsigned short* __restrict__ Mhat, unsigned short* __restrict__ KhatT,
    float* __restrict__ Pbuf)
{
    __shared__ float G[T_], Pl[T_], Bl[T_];
    __shared__ float L[T_][T_ + 1];
    __shared__ float X[T_][161];
    const int bh = blockIdx.x >> 6;
    const int c  = blockIdx.x & 63;
    const int b  = bh >> 4;
    const int h  = bh & 15;
    const int tid = threadIdx.x;
    const int tok0 = c * T_;
    const size_t qbase = (size_t)b * N_ * TRIPLE;
    const unsigned short* Kb = qkvc + qbase + 2048 + h * HD;
    const unsigned short* Qb = qkvc + qbase + h * HD;
    const unsigned short* Vb = qkvc + qbase + 4096 + h * HD;
    const float* abb = absig + (size_t)b * N_ * 32;

    if (tid < T_) {
        G[tid]  = __logf(abb[(tok0 + tid) * 32 + h]);
        Bl[tid] = abb[(tok0 + tid) * 32 + 16 + h];
    }
    __syncthreads();
    if (tid == 0) {
        float run = 0.f;
        for (int t = 0; t < T_; ++t) { run += G[t]; G[t] = run; Pl[t] = __expf(run); }
    }
    __syncthreads();
    if (tid < T_) Pbuf[((size_t)bh * NCHK + c) * T_ + tid] = Pl[tid];

    const int w = tid >> 6, lane = tid & 63;
    const int lr = lane & 15, lk8 = (lane >> 4) * 8, lrow4 = (lane >> 4) * 4;
    const int mt = w >> 1, nt = w & 1;

    f32x4v akk = {0.f,0.f,0.f,0.f}, aqk = {0.f,0.f,0.f,0.f};
    const unsigned short* Km = Kb + (size_t)(tok0 + mt * 16 + lr) * TRIPLE;
    const unsigned short* Qm = Qb + (size_t)(tok0 + mt * 16 + lr) * TRIPLE;
    const unsigned short* Kn = Kb + (size_t)(tok0 + nt * 16 + lr) * TRIPLE;
#pragma unroll
    for (int ks = 0; ks < 4; ++ks) {
        bf16x8 aK = *(const bf16x8*)(Km + ks * 32 + lk8);
        bf16x8 aQ = *(const bf16x8*)(Qm + ks * 32 + lk8);
        bf16x8 bK = *(const bf16x8*)(Kn + ks * 32 + lk8);
        akk = __builtin_amdgcn_mfma_f32_16x16x32_bf16(aK, bK, akk, 0, 0, 0);
        aqk = __builtin_amdgcn_mfma_f32_16x16x32_bf16(aQ, bK, aqk, 0, 0, 0);
    }
    unsigned short* Mg = Mhat + ((size_t)bh * NCHK + c) * (T_ * T_);
#pragma unroll
    for (int reg = 0; reg < 4; ++reg) {
        int t = mt * 16 + lrow4 + reg;
        int i = nt * 16 + lr;
        float dec = __expf(G[t] - G[i]);
        L[t][i] = (i < t) ? Bl[t] * dec * akk[reg] : 0.f;
        Mg[t * T_ + i] = (i <= t) ? f2bf(dec * aqk[reg]) : (unsigned short)0;
    }
    __syncthreads();

    for (int idx = tid; idx < T_ * HD; idx += 256) {
        int t = idx >> 7, e = idx & 127;
        X[t][e] = Bl[t] * bf2f(Vb[(size_t)(tok0 + t) * TRIPLE + e]);
    }
    for (int idx = tid; idx < T_ * T_; idx += 256) {
        int t = idx >> 5, i = idx & 31;
        X[t][HD + i] = (i == t) ? Bl[t] * Pl[t] : 0.f;
    }
    __syncthreads();

    if (tid < HD + T_) {
        float x[T_];
#pragma unroll
        for (int t = 0; t < T_; ++t) x[t] = X[t][tid];
#pragma unroll
        for (int t = 1; t < T_; ++t)
#pragma unroll
            for (int i = 0; i < t; ++i)
                x[t] -= L[t][i] * x[i];
        if (tid < HD) {
            float* Ug = Ubar + ((size_t)bh * NCHK + c) * (T_ * HD);
#pragma unroll
            for (int t = 0; t < T_; ++t) Ug[t * HD + tid] = x[t];
        } else {
            unsigned short* Wg = What + ((size_t)bh * NCHK + c) * (T_ * T_);
#pragma unroll
            for (int t = 0; t < T_; ++t) Wg[t * T_ + (tid - HD)] = f2bf(x[t]);
        }
    }

    unsigned short* Kg = KhatT + ((size_t)bh * NCHK + c) * (HD * T_);
    for (int idx = tid; idx < HD * T_; idx += 256) {
        int e = idx >> 5, t = idx & 31;
        float v = __expf(G[T_ - 1] - G[t]) * bf2f(Kb[(size_t)(tok0 + t) * TRIPLE + e]);
        Kg[idx] = f2bf(v);
    }
}

// Serial phase: 256 blocks = 32 bh x 8 d-slices of 16 rows.
__global__ __launch_bounds__(256) void chunk_scan(
    const unsigned short* __restrict__ qkvc, const float* __restrict__ gpre,
    const float* __restrict__ Ubar, const unsigned short* __restrict__ What,
    const unsigned short* __restrict__ Mhat, const unsigned short* __restrict__ KhatT,
    const float* __restrict__ Pbuf, unsigned short* __restrict__ og)
{
    __shared__ float          S  [16 * 132];
    __shared__ unsigned short Shi[16 * 136];
    __shared__ unsigned short Slo[16 * 136];
    __shared__ unsigned short CT [16 * 40];
    __shared__ unsigned short UT [16 * 40];

    const int blk = blockIdx.x;
    const int bh  = blk & 31;
    const int dsl = blk >> 5;
    const int b = bh >> 4, h = bh & 15;
    const int d0 = dsl * 16;
    const int tid = threadIdx.x;
    const int w = tid >> 6, lane = tid & 63;
    const int lr = lane & 15, lk8 = (lane >> 4) * 8, lrow4 = (lane >> 4) * 4;
    const int mt = w >> 1;
    const bool isQ = (w & 1);

    for (int i = tid; i < 16 * 132; i += 256) S[i] = 0.f;
    for (int i = tid; i < 16 * 136; i += 256) { Shi[i] = 0; Slo[i] = 0; }

    const size_t qbase = (size_t)b * N_ * TRIPLE;
    const unsigned short* Ab = qkvc + qbase + (isQ ? 0 : 2048) + h * HD;
    const float* gb = gpre + (size_t)b * N_ * INNER + h * HD;
    unsigned short* ogb = og + (size_t)b * N_ * INNER + h * HD;

    bf16x8 aF[4];
    bf16x8 wmF;
    float  sc4[4];
    float  g4[4];
    bf16x8 khF[2];
    float  gam;
    {
        const size_t cb = (size_t)bh * NCHK;
        const unsigned short* Am = Ab + (size_t)(mt * 16 + lr) * TRIPLE;
#pragma unroll
        for (int ks = 0; ks < 4; ++ks) aF[ks] = *(const bf16x8*)(Am + ks * 32 + lk8);
        if (!isQ) {
            wmF = *(const bf16x8*)(What + cb * (T_*T_) + (mt * 16 + lr) * T_ + lk8);
#pragma unroll
            for (int j = 0; j < 4; ++j)
                sc4[j] = Ubar[cb * (T_*HD) + (mt * 16 + lrow4 + j) * HD + d0 + lr];
        } else {
            wmF = *(const bf16x8*)(Mhat + cb * (T_*T_) + (mt * 16 + lr) * T_ + lk8);
#pragma unroll
            for (int j = 0; j < 4; ++j) {
                sc4[j] = Pbuf[cb * T_ + mt * 16 + lrow4 + j];
                g4[j]  = gb[(size_t)(mt * 16 + lrow4 + j) * INNER + d0 + lr];
            }
        }
#pragma unroll
        for (int j2 = 0; j2 < 2; ++j2)
            khF[j2] = *(const bf16x8*)(KhatT + cb * (HD*T_) + ((2*w + j2) * 16 + lr) * T_ + lk8);
        gam = Pbuf[cb * T_ + T_ - 1];
    }
    __syncthreads();

    for (int c = 0; c < NCHK; ++c) {
        const int np = (c + 1 < NCHK) ? c + 1 : c;
        const size_t cbn = (size_t)bh * NCHK + np;
        const int tok0n = np * T_;
        bf16x8 aFn[4], wmFn, khFn[2];
        float sc4n[4], g4n[4], gamn;
        {
            const unsigned short* Am = Ab + (size_t)(tok0n + mt * 16 + lr) * TRIPLE;
#pragma unroll
            for (int ks = 0; ks < 4; ++ks) aFn[ks] = *(const bf16x8*)(Am + ks * 32 + lk8);
            if (!isQ) {
                wmFn = *(const bf16x8*)(What + cbn * (T_*T_) + (mt * 16 + lr) * T_ + lk8);
#pragma unroll
                for (int j = 0; j < 4; ++j)
                    sc4n[j] = Ubar[cbn * (T_*HD) + (mt * 16 + lrow4 + j) * HD + d0 + lr];
            } else {
                wmFn = *(const bf16x8*)(Mhat + cbn * (T_*T_) + (mt * 16 + lr) * T_ + lk8);
#pragma unroll
                for (int j = 0; j < 4; ++j) {
                    sc4n[j] = Pbuf[cbn * T_ + mt * 16 + lrow4 + j];
                    g4n[j]  = gb[(size_t)(tok0n + mt * 16 + lrow4 + j) * INNER + d0 + lr];
                }
            }
#pragma unroll
            for (int j2 = 0; j2 < 2; ++j2)
                khFn[j2] = *(const bf16x8*)(KhatT + cbn * (HD*T_) + ((2*w + j2) * 16 + lr) * T_ + lk8);
            gamn = Pbuf[cbn * T_ + T_ - 1];
        }

        f32x4v accH = {0.f,0.f,0.f,0.f}, accL = {0.f,0.f,0.f,0.f};
#pragma unroll
        for (int ks = 0; ks < 4; ++ks) {
            bf16x8 hi = *(const bf16x8*)&Shi[lr * 136 + ks * 32 + lk8];
            bf16x8 lo = *(const bf16x8*)&Slo[lr * 136 + ks * 32 + lk8];
            accH = __builtin_amdgcn_mfma_f32_16x16x32_bf16(aF[ks], hi, accH, 0, 0, 0);
            accL = __builtin_amdgcn_mfma_f32_16x16x32_bf16(aF[ks], lo, accL, 0, 0, 0);
        }
        f32x4v accB;
#pragma unroll
        for (int j = 0; j < 4; ++j) accB[j] = accH[j] + accL[j];

        if (!isQ) {
            ushort4 cv;
            cv.x = f2bf(-accB[0]); cv.y = f2bf(-accB[1]);
            cv.z = f2bf(-accB[2]); cv.w = f2bf(-accB[3]);
            *(ushort4*)&CT[lr * 40 + mt * 16 + lrow4] = cv;
        }
        lds_barrier();

        if (!isQ) {
            f32x4v accU;
#pragma unroll
            for (int j = 0; j < 4; ++j) accU[j] = sc4[j];
            bf16x8 bC = *(const bf16x8*)&CT[lr * 40 + lk8];
            accU = __builtin_amdgcn_mfma_f32_16x16x32_bf16(wmF, bC, accU, 0, 0, 0);
            ushort4 uv;
            uv.x = f2bf(accU[0]); uv.y = f2bf(accU[1]);
            uv.z = f2bf(accU[2]); uv.w = f2bf(accU[3]);
            *(ushort4*)&UT[lr * 40 + mt * 16 + lrow4] = uv;
        }
        lds_barrier();

        bf16x8 utF = *(const bf16x8*)&UT[lr * 40 + lk8];

        if (isQ) {
            f32x4v accO;
#pragma unroll
            for (int j = 0; j < 4; ++j) accO[j] = sc4[j] * accB[j];
            accO = __builtin_amdgcn_mfma_f32_16x16x32_bf16(wmF, utF, accO, 0, 0, 0);
            const int tokb = c * T_ + mt * 16 + lrow4;
#pragma unroll
            for (int j = 0; j < 4; ++j)
                ogb[(size_t)(tokb + j) * INNER + d0 + lr] = f2bf(accO[j] * g4[j]);
        }

#pragma unroll
        for (int j2 = 0; j2 < 2; ++j2) {
            const int et = 2 * w + j2;
            f32x4v accS;
#pragma unroll
            for (int j = 0; j < 4; ++j)
                accS[j] = gam * S[(lrow4 + j) * 132 + et * 16 + lr];
            accS = __builtin_amdgcn_mfma_f32_16x16x32_bf16(utF, khF[j2], accS, 0, 0, 0);
#pragma unroll
            for (int j = 0; j < 4; ++j) {
                float v = accS[j];
                S[(lrow4 + j) * 132 + et * 16 + lr] = v;
                unsigned short hh = f2bf(v);
                Shi[(lrow4 + j) * 136 + et * 16 + lr] = hh;
                Slo[(lrow4 + j) * 136 + et * 16 + lr] = f2bf(v - bf2f(hh));
            }
        }
        lds_barrier();

#pragma unroll
        for (int ks = 0; ks < 4; ++ks) aF[ks] = aFn[ks];
        wmF = wmFn;
#pragma unroll
        for (int j = 0; j < 4; ++j) { sc4[j] = sc4n[j]; g4[j] = g4n[j]; }
        khF[0] = khFn[0]; khF[1] = khFn[1];
        gam = gamn;
    }
}

extern "C" void kernel_launch(void* const* d_in, const int* in_sizes, int n_in,
                              void* d_out, int out_size, void* d_ws, size_t ws_size,
                              hipStream_t stream) {
    const float* x      = (const float*)d_in[0];
    const float* W_qkv  = (const float*)d_in[1];
    const float* conv_w = (const float*)d_in[2];
    const float* W_ab   = (const float*)d_in[3];
    const float* b_ab   = (const float*)d_in[4];
    const float* W_g    = (const float*)d_in[5];
    const float* W_o    = (const float*)d_in[6];
    float* out = (float*)d_out;

    // Workspace layout. wqkvb region (TRIPLE+INNER rows) now holds the
    // 16x32-TILED packed fused weights (same byte count). wob is linear.
    char* p = (char*)d_ws;
    unsigned short* wqkvb   = (unsigned short*)p; p += (size_t)TRIPLE * DM * 2;
    unsigned short* wgb     = (unsigned short*)p; p += (size_t)INNER * DM * 2;   // part of packed region
    unsigned short* wob     = (unsigned short*)p; p += (size_t)DM * INNER * 2;
    unsigned short* wabhi   = (unsigned short*)p; p += (size_t)32 * DM * 2;
    unsigned short* wablo   = (unsigned short*)p; p += (size_t)32 * DM * 2;
    unsigned short* xb      = (unsigned short*)p; p += (size_t)M_ * DM * 2;
    unsigned short* xlo     = (unsigned short*)p; p += (size_t)M_ * DM * 2;
    unsigned short* qkv_pre = (unsigned short*)p; p += (size_t)M_ * TRIPLE * 2;
    unsigned short* qkv_c   = (unsigned short*)p; p += (size_t)M_ * TRIPLE * 2;
    float*          absig   = (float*)p;          p += (size_t)M_ * 32 * 4;
    float*          gpre    = (float*)p;          p += (size_t)M_ * INNER * 4;
    unsigned short* ogb     = (unsigned short*)p; p += (size_t)M_ * INNER * 2;
    (void)wgb;

    // chunk buffers overlay xb..qkv_pre (dead after gemm_ab / conv)
    char* q = (char*)xb;
    float*          Ubar  = (float*)q;          q += (size_t)32 * NCHK * T_ * HD * 4;
    unsigned short* KhatT = (unsigned short*)q; q += (size_t)32 * NCHK * HD * T_ * 2;
    unsigned short* What  = (unsigned short*)q; q += (size_t)32 * NCHK * T_ * T_ * 2;
    unsigned short* Mhat  = (unsigned short*)q; q += (size_t)32 * NCHK * T_ * T_ * 2;
    float*          Pbuf  = (float*)q;          q += (size_t)32 * NCHK * T_ * 4;

    dim3 blk(256);
    cast_hilo<<<dim3((M_ * DM) / 1024), blk, 0, stream>>>(x, xb, xlo, M_ * DM);
    // pack W_qkv+W_g into 16x32-tiled bf16 (for register-direct B loads)
    pack_cast_w<<<dim3(((TRIPLE + INNER) * DM / 8) / 256), blk, 0, stream>>>(
        W_qkv, W_g, wqkvb);
    cast_bf16<<<dim3((INNER * DM) / 1024), blk, 0, stream>>>(W_o, wob, INNER * DM);
    cast_hilo<<<dim3((32 * DM) / 1024), blk, 0, stream>>>(W_ab, wabhi, wablo, 32 * DM);

    // fused: qkv (bf16) + g (fp32 silu) — A-in-LDS + B-register-direct
    gemm_fused256<<<dim3(((TRIPLE + INNER) / 256) * (M_ / 256)), dim3(512), 0, stream>>>(
        xb, wqkvb, qkv_pre, gpre, M_, TRIPLE, INNER, DM);
    // ab (split-bf16, fp32-grade) + sigmoid — K-split 4 ways, 256 blocks
    gemm_ab<<<dim3(M_ / 16), blk, 0, stream>>>(xb, xlo, wabhi, wablo, b_ab, absig);
    // conv + silu + l2norm (vectorized)
    conv_silu_norm<<<dim3(B_ * N_), blk, 0, stream>>>(qkv_pre, conv_w, qkv_c);

    chunk_prep<<<dim3(32 * NCHK), blk, 0, stream>>>(qkv_c, absig, Ubar, What, Mhat, KhatT, Pbuf);
    chunk_scan<<<dim3(256), blk, 0, stream>>>(qkv_c, gpre, Ubar, What, Mhat, KhatT, Pbuf, ogb);

    // W_o projection — 128^2-tile dbuf counted-vmcnt pipeline (2 blocks/CU)
    gemm_bf16f<<<dim3((M_ / 128) * (INNER / 128)), blk, 0, stream>>>(
        ogb, wob, out, M_, INNER, DM);
}

// Round 6
// 580.732 us; speedup vs baseline: 1.0074x; 1.0074x over previous
//
#include <hip/hip_runtime.h>
#include <math.h>
#include <stddef.h>

#define B_ 2
#define N_ 2048
#define DM 2048
#define H_ 16
#define HD 128
#define INNER 2048
#define TRIPLE 6144
#define M_ (B_ * N_)   // 4096
#define T_ 32          // chunk length
#define NCHK (N_ / T_) // 64 chunks

typedef __bf16 bf16x8 __attribute__((ext_vector_type(8)));
typedef float  f32x4v __attribute__((ext_vector_type(4)));
typedef __attribute__((address_space(1))) const void gvoid;
typedef __attribute__((address_space(3))) void lvoid;

__device__ __forceinline__ float sig_(float x) { return 1.0f / (1.0f + __expf(-x)); }

__device__ __forceinline__ unsigned short f2bf(float f) {
    unsigned u = __float_as_uint(f);
    u += 0x7FFFu + ((u >> 16) & 1u);     // RNE
    return (unsigned short)(u >> 16);
}
__device__ __forceinline__ float bf2f(unsigned short h) {
    return __uint_as_float((unsigned)h << 16);
}
__device__ __forceinline__ void unpack8(uint4 r, float* f) {
    f[0] = __uint_as_float(r.x << 16); f[1] = __uint_as_float(r.x & 0xffff0000u);
    f[2] = __uint_as_float(r.y << 16); f[3] = __uint_as_float(r.y & 0xffff0000u);
    f[4] = __uint_as_float(r.z << 16); f[5] = __uint_as_float(r.z & 0xffff0000u);
    f[6] = __uint_as_float(r.w << 16); f[7] = __uint_as_float(r.w & 0xffff0000u);
}

// Workgroup barrier that waits ONLY on LDS ops (lgkmcnt(0)); prefetched
// global loads stay in flight across it.
__device__ __forceinline__ void lds_barrier() {
    asm volatile("" ::: "memory");
    __builtin_amdgcn_s_waitcnt(0xC07F);
    __builtin_amdgcn_s_barrier();
    asm volatile("" ::: "memory");
}

// Raw barrier: NO waitcnt drain (counted-vmcnt pipeline crosses it).
__device__ __forceinline__ void bar() {
    asm volatile("" ::: "memory");
    __builtin_amdgcn_s_barrier();
    asm volatile("" ::: "memory");
}

// ============================================================================
// ONE launch for all input casts (launch gap ~5-7us each; R3's cast merge
// measurably saved ~15us). Regions (4-elem granular, all sizes /4):
//  [0, NX)            : x -> hi/lo split (xb, xlo)
//  [NX, NX+NW)        : [W_qkv | W_g | W_o] -> bf16 into contiguous wfused
//  [NX+NW, +NAB)      : W_ab -> hi/lo split (wabhi, wablo)
// ============================================================================
#define NX_ (M_ * DM)                       // 8,388,608
#define NW_ ((TRIPLE + 2 * INNER) * DM)     // 20,971,520
#define NAB_ (32 * DM)                      // 65,536
__global__ __launch_bounds__(256) void cast_all(
    const float* __restrict__ x, const float* __restrict__ Wq,
    const float* __restrict__ Wg, const float* __restrict__ Wo,
    const float* __restrict__ Wab,
    unsigned short* __restrict__ xb, unsigned short* __restrict__ xlo,
    unsigned short* __restrict__ wfused,
    unsigned short* __restrict__ wabhi, unsigned short* __restrict__ wablo)
{
    const int i = (blockIdx.x * 256 + threadIdx.x) * 4;
    if (i < NX_) {
        float4 v = *(const float4*)(x + i);
        ushort4 h, l;
        h.x = f2bf(v.x); l.x = f2bf(v.x - bf2f(h.x));
        h.y = f2bf(v.y); l.y = f2bf(v.y - bf2f(h.y));
        h.z = f2bf(v.z); l.z = f2bf(v.z - bf2f(h.z));
        h.w = f2bf(v.w); l.w = f2bf(v.w - bf2f(h.w));
        *(ushort4*)(xb + i)  = h;
        *(ushort4*)(xlo + i) = l;
    } else if (i < NX_ + NW_) {
        const int j = i - NX_;
        const float* s;
        if (j < TRIPLE * DM)                s = Wq + j;
        else if (j < (TRIPLE + INNER) * DM) s = Wg + (j - TRIPLE * DM);
        else                                s = Wo + (j - (TRIPLE + INNER) * DM);
        float4 v = *(const float4*)s;
        ushort4 u;
        u.x = f2bf(v.x); u.y = f2bf(v.y); u.z = f2bf(v.z); u.w = f2bf(v.w);
        *(ushort4*)(wfused + j) = u;
    } else if (i < NX_ + NW_ + NAB_) {
        const int j = i - NX_ - NW_;
        float4 v = *(const float4*)(Wab + j);
        ushort4 h, l;
        h.x = f2bf(v.x); l.x = f2bf(v.x - bf2f(h.x));
        h.y = f2bf(v.y); l.y = f2bf(v.y - bf2f(h.y));
        h.z = f2bf(v.z); l.z = f2bf(v.z - bf2f(h.z));
        h.w = f2bf(v.w); l.w = f2bf(v.w - bf2f(h.w));
        *(ushort4*)(wabhi + j) = h;
        *(ushort4*)(wablo + j) = l;
    }
}

// ============================================================================
// Fused (qkv | g) GEMM, R6: 128x128 tile on the PROVEN gemm_bf16f skeleton
// (R4's fastest per-FLOP GEMM, ~1150 TF): BK=64, double-buffered LDS (64 KiB
// -> 2 blocks/CU, cross-block stall absorption per m114), counted vmcnt(8),
// 2 barriers/tile, XOR swizzle (0 conflicts), XCD swizzle (2048 blocks).
// R5's B-register-direct experiment REVERTED (202us: B through the per-CU
// TCP VGPR-return path serializes ~1000cyc/tile; LDS broadcast was the win).
// Per-element accumulation order identical to fused256 -> bitwise-same out.
//  Per tile: RD 16 frags (buf cur) | bar1 | STAGE tile kt+2 -> buf cur |
//            32 MFMA (ks-outer) | vmcnt(8) retires tile kt+1 | bar2.
// ============================================================================
__global__ __launch_bounds__(256) void gemm_fused128(
    const unsigned short* __restrict__ A, const unsigned short* __restrict__ Bw,
    unsigned short* __restrict__ outQ, float* __restrict__ outG,
    int M, int NQ, int NG, int K)
{
    __shared__ unsigned short As[2][128 * 64];
    __shared__ unsigned short Bs[2][128 * 64];

    const int tid = threadIdx.x;
    const int w   = tid >> 6;      // 0..3
    const int l   = tid & 63;
    const int wm  = w >> 1;        // 0..1
    const int wn  = w & 1;         // 0..1
    const int lr  = l & 15;
    const int kg  = l >> 4;        // 0..3

    // XCD swizzle: grid = (M/128)*(N/128) = 32*64 = 2048 blocks (2048%8==0)
    const int bid = blockIdx.x;
    const int swz = (bid & 7) * 256 + (bid >> 3);
    const int by  = swz & 31;      // 32 row-tiles (M=4096)
    const int bx  = swz >> 5;      // 64 col-tiles (N=8192)
    const int row0 = by * 128;
    const int col0 = bx * 128;

    const int srow = w * 8 + (l >> 3);           // 0..31
    const int schk = ((l & 7) ^ (l >> 3)) * 8;   // pre-swizzled source chunk
    const unsigned short* Ath = A  + (size_t)(row0 + srow) * K + schk;
    const unsigned short* Bth = Bw + (size_t)(col0 + srow) * K + schk;

    const int fsw0 = ((0 + kg) ^ (lr & 7)) * 8;
    const int fsw1 = ((4 + kg) ^ (lr & 7)) * 8;
    const int arb  = wm * 64 + lr;
    const int brb  = wn * 64 + lr;

    f32x4v acc[4][4];
#pragma unroll
    for (int i = 0; i < 4; ++i)
#pragma unroll
        for (int j = 0; j < 4; ++j) acc[i][j] = (f32x4v){0.f, 0.f, 0.f, 0.f};

#define STAGE_F(buf, kt) do {                                                    \
        _Pragma("unroll")                                                        \
        for (int p_ = 0; p_ < 4; ++p_) {                                         \
            const unsigned short* ga_ = Ath + (size_t)(p_ * 32) * K + (kt) * 64; \
            const unsigned short* gb_ = Bth + (size_t)(p_ * 32) * K + (kt) * 64; \
            unsigned short* da_ = &As[buf][(p_ * 32 + w * 8) * 64];              \
            unsigned short* db_ = &Bs[buf][(p_ * 32 + w * 8) * 64];              \
            __builtin_amdgcn_global_load_lds((gvoid*)ga_, (lvoid*)da_, 16, 0, 0);\
            __builtin_amdgcn_global_load_lds((gvoid*)gb_, (lvoid*)db_, 16, 0, 0);\
        }                                                                        \
    } while (0)

    const int KT = K >> 6;   // 32

    STAGE_F(0, 0);
    STAGE_F(1, 1);
    asm volatile("s_waitcnt vmcnt(8)" ::: "memory");
    bar();

    bf16x8 aF[4][2], bF[4][2];

#pragma unroll 2
    for (int kt = 0; kt < KT; ++kt) {
        const unsigned short* Ab = As[kt & 1];
        const unsigned short* Bb = Bs[kt & 1];

#pragma unroll
        for (int m_ = 0; m_ < 4; ++m_) {
            const int r_ = (arb + m_ * 16) * 64;
            aF[m_][0] = *(const bf16x8*)(Ab + r_ + fsw0);
            aF[m_][1] = *(const bf16x8*)(Ab + r_ + fsw1);
        }
#pragma unroll
        for (int n_ = 0; n_ < 4; ++n_) {
            const int r_ = (brb + n_ * 16) * 64;
            bF[n_][0] = *(const bf16x8*)(Bb + r_ + fsw0);
            bF[n_][1] = *(const bf16x8*)(Bb + r_ + fsw1);
        }
        bar();                                    // all reads of buf cur done

        if (kt + 2 < KT) STAGE_F(kt & 1, kt + 2); // restage into buf just read

        __builtin_amdgcn_s_setprio(1);
#pragma unroll
        for (int ks = 0; ks < 2; ++ks)
#pragma unroll
            for (int m_ = 0; m_ < 4; ++m_)
#pragma unroll
                for (int n_ = 0; n_ < 4; ++n_)
                    acc[m_][n_] = __builtin_amdgcn_mfma_f32_16x16x32_bf16(
                        aF[m_][ks], bF[n_][ks], acc[m_][n_], 0, 0, 0);
        __builtin_amdgcn_s_setprio(0);

        if (kt < KT - 2) {
            asm volatile("s_waitcnt vmcnt(8)" ::: "memory");
        } else if (kt == KT - 2) {
            asm volatile("s_waitcnt vmcnt(0)" ::: "memory");
        }
        bar();
    }
#undef STAGE_F

    // epilogue: qkv region -> bf16; g region -> silu fp32. NQ=6144=48*128,
    // so isG is block-uniform.
    const bool isG = (col0 >= NQ);
#pragma unroll
    for (int m_ = 0; m_ < 4; ++m_)
#pragma unroll
        for (int j = 0; j < 4; ++j) {
            const int r = row0 + wm * 64 + m_ * 16 + kg * 4 + j;
#pragma unroll
            for (int n_ = 0; n_ < 4; ++n_) {
                const int c = col0 + wn * 64 + n_ * 16 + lr;
                float v = acc[m_][n_][j];
                if (!isG) {
                    outQ[(size_t)r * NQ + c] = f2bf(v);
                } else {
                    v = v * sig_(v);
                    outG[(size_t)r * NG + (c - NQ)] = v;
                }
            }
        }
}

// ============================================================================
// W_o projection GEMM (fp32 out): 128x128 tile, BK=64, double-buffered LDS
// (64 KiB -> 2 blocks/CU), counted vmcnt(8), 2 barriers/tile, XOR swizzle,
// XCD swizzle. (R4 kernel, unchanged.)
// ============================================================================
__global__ __launch_bounds__(256) void gemm_bf16f(
    const unsigned short* __restrict__ A, const unsigned short* __restrict__ Bw,
    float* __restrict__ C, int M, int N, int K)
{
    __shared__ unsigned short As[2][128 * 64];
    __shared__ unsigned short Bs[2][128 * 64];

    const int tid = threadIdx.x;
    const int w   = tid >> 6;      // 0..3
    const int l   = tid & 63;
    const int wm  = w >> 1;        // 0..1
    const int wn  = w & 1;         // 0..1
    const int lr  = l & 15;
    const int kg  = l >> 4;        // 0..3

    const int bid = blockIdx.x;
    const int swz = (bid & 7) * 64 + (bid >> 3);
    const int by  = swz & 31;      // 32 row-tiles (M=4096)
    const int bx  = swz >> 5;      // 16 col-tiles (N=2048)
    const int row0 = by * 128;
    const int col0 = bx * 128;

    const int srow = w * 8 + (l >> 3);           // 0..31
    const int schk = ((l & 7) ^ (l >> 3)) * 8;
    const unsigned short* Ath = A  + (size_t)(row0 + srow) * K + schk;
    const unsigned short* Bth = Bw + (size_t)(col0 + srow) * K + schk;

    const int fsw0 = ((0 + kg) ^ (lr & 7)) * 8;
    const int fsw1 = ((4 + kg) ^ (lr & 7)) * 8;
    const int arb  = wm * 64 + lr;
    const int brb  = wn * 64 + lr;

    f32x4v acc[4][4];
#pragma unroll
    for (int i = 0; i < 4; ++i)
#pragma unroll
        for (int j = 0; j < 4; ++j) acc[i][j] = (f32x4v){0.f, 0.f, 0.f, 0.f};

#define STAGE_T(buf, kt) do {                                                    \
        _Pragma("unroll")                                                        \
        for (int p_ = 0; p_ < 4; ++p_) {                                         \
            const unsigned short* ga_ = Ath + (size_t)(p_ * 32) * K + (kt) * 64; \
            const unsigned short* gb_ = Bth + (size_t)(p_ * 32) * K + (kt) * 64; \
            unsigned short* da_ = &As[buf][(p_ * 32 + w * 8) * 64];              \
            unsigned short* db_ = &Bs[buf][(p_ * 32 + w * 8) * 64];              \
            __builtin_amdgcn_global_load_lds((gvoid*)ga_, (lvoid*)da_, 16, 0, 0);\
            __builtin_amdgcn_global_load_lds((gvoid*)gb_, (lvoid*)db_, 16, 0, 0);\
        }                                                                        \
    } while (0)

    const int KT = K >> 6;   // 32

    STAGE_T(0, 0);
    STAGE_T(1, 1);
    asm volatile("s_waitcnt vmcnt(8)" ::: "memory");
    bar();

    bf16x8 aF[4][2], bF[4][2];

#pragma unroll 2
    for (int kt = 0; kt < KT; ++kt) {
        const unsigned short* Ab = As[kt & 1];
        const unsigned short* Bb = Bs[kt & 1];

#pragma unroll
        for (int m_ = 0; m_ < 4; ++m_) {
            const int r_ = (arb + m_ * 16) * 64;
            aF[m_][0] = *(const bf16x8*)(Ab + r_ + fsw0);
            aF[m_][1] = *(const bf16x8*)(Ab + r_ + fsw1);
        }
#pragma unroll
        for (int n_ = 0; n_ < 4; ++n_) {
            const int r_ = (brb + n_ * 16) * 64;
            bF[n_][0] = *(const bf16x8*)(Bb + r_ + fsw0);
            bF[n_][1] = *(const bf16x8*)(Bb + r_ + fsw1);
        }
        bar();                                    // all reads of buf cur done

        if (kt + 2 < KT) STAGE_T(kt & 1, kt + 2);

        __builtin_amdgcn_s_setprio(1);
#pragma unroll
        for (int ks = 0; ks < 2; ++ks)
#pragma unroll
            for (int m_ = 0; m_ < 4; ++m_)
#pragma unroll
                for (int n_ = 0; n_ < 4; ++n_)
                    acc[m_][n_] = __builtin_amdgcn_mfma_f32_16x16x32_bf16(
                        aF[m_][ks], bF[n_][ks], acc[m_][n_], 0, 0, 0);
        __builtin_amdgcn_s_setprio(0);

        if (kt < KT - 2) {
            asm volatile("s_waitcnt vmcnt(8)" ::: "memory");
        } else if (kt == KT - 2) {
            asm volatile("s_waitcnt vmcnt(0)" ::: "memory");
        }
        bar();
    }
#undef STAGE_T

#pragma unroll
    for (int m_ = 0; m_ < 4; ++m_)
#pragma unroll
        for (int j = 0; j < 4; ++j) {
            const int r = row0 + wm * 64 + m_ * 16 + kg * 4 + j;
#pragma unroll
            for (int n_ = 0; n_ < 4; ++n_) {
                const int c = col0 + wn * 64 + n_ * 16 + lr;
                C[(size_t)r * N + c] = acc[m_][n_][j];
            }
        }
}

// ab = sigmoid(x @ W_ab^T + b_ab) via split-bf16 MFMA (fp32-grade).
// 256 blocks x 16 rows; 4 waves split K 4-ways, LDS reduce.
__global__ __launch_bounds__(256) void gemm_ab(
    const unsigned short* __restrict__ xhi, const unsigned short* __restrict__ xlo,
    const unsigned short* __restrict__ wh, const unsigned short* __restrict__ wl,
    const float* __restrict__ b_ab, float* __restrict__ absig)
{
    __shared__ float sums[4][16][32];
    const int tid = threadIdx.x;
    const int w = tid >> 6, lane = tid & 63;
    const int lr = lane & 15, lk8 = (lane >> 4) * 8, lrow4 = (lane >> 4) * 4;
    const int row = blockIdx.x * 16 + lr;
    const int kw  = w * (DM / 4);    // per-wave K-chunk base

    f32x4v acc[2];
    acc[0] = (f32x4v){0.f,0.f,0.f,0.f};
    acc[1] = (f32x4v){0.f,0.f,0.f,0.f};
    const unsigned short* Ah = xhi + (size_t)row * DM + kw;
    const unsigned short* Al = xlo + (size_t)row * DM + kw;

    for (int k0 = 0; k0 < DM / 4; k0 += 32) {
        bf16x8 ah = *(const bf16x8*)(Ah + k0 + lk8);
        bf16x8 al = *(const bf16x8*)(Al + k0 + lk8);
#pragma unroll
        for (int nt = 0; nt < 2; ++nt) {
            bf16x8 whf = *(const bf16x8*)(wh + (size_t)(nt * 16 + lr) * DM + kw + k0 + lk8);
            bf16x8 wlf = *(const bf16x8*)(wl + (size_t)(nt * 16 + lr) * DM + kw + k0 + lk8);
            acc[nt] = __builtin_amdgcn_mfma_f32_16x16x32_bf16(ah, whf, acc[nt], 0, 0, 0);
            acc[nt] = __builtin_amdgcn_mfma_f32_16x16x32_bf16(ah, wlf, acc[nt], 0, 0, 0);
            acc[nt] = __builtin_amdgcn_mfma_f32_16x16x32_bf16(al, whf, acc[nt], 0, 0, 0);
        }
    }

#pragma unroll
    for (int nt = 0; nt < 2; ++nt)
#pragma unroll
        for (int j = 0; j < 4; ++j)
            sums[w][lrow4 + j][nt * 16 + lr] = acc[nt][j];
    __syncthreads();

    for (int e = tid; e < 512; e += 256) {
        const int r = e >> 5, c = e & 31;
        float s = sums[0][r][c] + sums[1][r][c] + sums[2][r][c] + sums[3][r][c];
        absig[(size_t)(blockIdx.x * 16 + r) * 32 + c] = sig_(s + b_ab[c]);
    }
}

// conv(K=4, causal, depthwise) + silu + per-head l2norm of q,k.
// Vectorized bf16x8 IO; fp32 accumulation and norm.
__global__ __launch_bounds__(256) void conv_silu_norm(
    const unsigned short* __restrict__ qkv, const float* __restrict__ conv_w,
    unsigned short* __restrict__ outb)
{
    __shared__ float buf[TRIPLE];
    __shared__ float scales[32];
    const int bn = blockIdx.x;
    const int n = bn & (N_ - 1);
    const int tid = threadIdx.x;
    const unsigned short* base = qkv + (size_t)bn * TRIPLE;

#pragma unroll
    for (int it = 0; it < 3; ++it) {
        const int c8 = (tid + it * 256) * 8;
        float cw[32];
#pragma unroll
        for (int q4 = 0; q4 < 8; ++q4)
            *(float4*)&cw[q4 * 4] = *(const float4*)(conv_w + (size_t)c8 * 4 + q4 * 4);
        float acc[8] = {0.f,0.f,0.f,0.f,0.f,0.f,0.f,0.f};
#pragma unroll
        for (int j = 0; j < 4; ++j) {
            if (n - 3 + j >= 0) {
                uint4 r = *(const uint4*)(base + (ptrdiff_t)(j - 3) * TRIPLE + c8);
                float xf[8]; unpack8(r, xf);
#pragma unroll
                for (int e = 0; e < 8; ++e) acc[e] += xf[e] * cw[e * 4 + j];
            }
        }
        float4 o0, o1;
        o0.x = acc[0] * sig_(acc[0]); o0.y = acc[1] * sig_(acc[1]);
        o0.z = acc[2] * sig_(acc[2]); o0.w = acc[3] * sig_(acc[3]);
        o1.x = acc[4] * sig_(acc[4]); o1.y = acc[5] * sig_(acc[5]);
        o1.z = acc[6] * sig_(acc[6]); o1.w = acc[7] * sig_(acc[7]);
        *(float4*)&buf[c8] = o0;
        *(float4*)&buf[c8 + 4] = o1;
    }
    __syncthreads();

    const int g = tid >> 3, l = tid & 7;
    {
        int off = (g < 16) ? g * HD : 2048 + (g - 16) * HD;
        float s = 0.f;
        for (int i = l; i < HD; i += 8) { float v = buf[off + i]; s += v * v; }
        s += __shfl_xor(s, 1); s += __shfl_xor(s, 2); s += __shfl_xor(s, 4);
        if (l == 0) scales[g] = 1.0f / fmaxf(sqrtf(s), 1e-12f);
    }
    __syncthreads();

    unsigned short* ob = outb + (size_t)bn * TRIPLE;
#pragma unroll
    for (int it = 0; it < 3; ++it) {
        const int c8 = (tid + it * 256) * 8;
        float sc = 1.f;
        if (c8 < 2048) sc = scales[c8 >> 7];
        else if (c8 < 4096) sc = scales[16 + ((c8 - 2048) >> 7)];
        float4 f0 = *(const float4*)&buf[c8];
        float4 f1 = *(const float4*)&buf[c8 + 4];
        ushort4 u0, u1;
        u0.x = f2bf(f0.x * sc); u0.y = f2bf(f0.y * sc);
        u0.z = f2bf(f0.z * sc); u0.w = f2bf(f0.w * sc);
        u1.x = f2bf(f1.x * sc); u1.y = f2bf(f1.y * sc);
        u1.z = f2bf(f1.z * sc); u1.w = f2bf(f1.w * sc);
        *(ushort4*)(ob + c8) = u0;
        *(ushort4*)(ob + c8 + 4) = u1;
    }
}

// ---------------- chunked delta rule ----------------
__global__ __launch_bounds__(256) void chunk_prep(
    const unsigned short* __restrict__ qkvc, const float* __restrict__ absig,
    float* __restrict__ Ubar, unsigned short* __restrict__ What,
    unsigned short* __restrict__ Mhat, unsigned short* __restrict__ KhatT,
    float* __restrict__ Pbuf)
{
    __shared__ float G[T_], Pl[T_], Bl[T_];
    __shared__ float L[T_][T_ + 1];
    __shared__ float X[T_][161];
    const int bh = blockIdx.x >> 6;
    const int c  = blockIdx.x & 63;
    const int b  = bh >> 4;
    const int h  = bh & 15;
    const int tid = threadIdx.x;
    const int tok0 = c * T_;
    const size_t qbase = (size_t)b * N_ * TRIPLE;
    const unsigned short* Kb = qkvc + qbase + 2048 + h * HD;
    const unsigned short* Qb = qkvc + qbase + h * HD;
    const unsigned short* Vb = qkvc + qbase + 4096 + h * HD;
    const float* abb = absig + (size_t)b * N_ * 32;

    if (tid < T_) {
        G[tid]  = __logf(abb[(tok0 + tid) * 32 + h]);
        Bl[tid] = abb[(tok0 + tid) * 32 + 16 + h];
    }
    __syncthreads();
    if (tid == 0) {
        float run = 0.f;
        for (int t = 0; t < T_; ++t) { run += G[t]; G[t] = run; Pl[t] = __expf(run); }
    }
    __syncthreads();
    if (tid < T_) Pbuf[((size_t)bh * NCHK + c) * T_ + tid] = Pl[tid];

    const int w = tid >> 6, lane = tid & 63;
    const int lr = lane & 15, lk8 = (lane >> 4) * 8, lrow4 = (lane >> 4) * 4;
    const int mt = w >> 1, nt = w & 1;

    f32x4v akk = {0.f,0.f,0.f,0.f}, aqk = {0.f,0.f,0.f,0.f};
    const unsigned short* Km = Kb + (size_t)(tok0 + mt * 16 + lr) * TRIPLE;
    const unsigned short* Qm = Qb + (size_t)(tok0 + mt * 16 + lr) * TRIPLE;
    const unsigned short* Kn = Kb + (size_t)(tok0 + nt * 16 + lr) * TRIPLE;
#pragma unroll
    for (int ks = 0; ks < 4; ++ks) {
        bf16x8 aK = *(const bf16x8*)(Km + ks * 32 + lk8);
        bf16x8 aQ = *(const bf16x8*)(Qm + ks * 32 + lk8);
        bf16x8 bK = *(const bf16x8*)(Kn + ks * 32 + lk8);
        akk = __builtin_amdgcn_mfma_f32_16x16x32_bf16(aK, bK, akk, 0, 0, 0);
        aqk = __builtin_amdgcn_mfma_f32_16x16x32_bf16(aQ, bK, aqk, 0, 0, 0);
    }
    unsigned short* Mg = Mhat + ((size_t)bh * NCHK + c) * (T_ * T_);
#pragma unroll
    for (int reg = 0; reg < 4; ++reg) {
        int t = mt * 16 + lrow4 + reg;
        int i = nt * 16 + lr;
        float dec = __expf(G[t] - G[i]);
        L[t][i] = (i < t) ? Bl[t] * dec * akk[reg] : 0.f;
        Mg[t * T_ + i] = (i <= t) ? f2bf(dec * aqk[reg]) : (unsigned short)0;
    }
    __syncthreads();

    for (int idx = tid; idx < T_ * HD; idx += 256) {
        int t = idx >> 7, e = idx & 127;
        X[t][e] = Bl[t] * bf2f(Vb[(size_t)(tok0 + t) * TRIPLE + e]);
    }
    for (int idx = tid; idx < T_ * T_; idx += 256) {
        int t = idx >> 5, i = idx & 31;
        X[t][HD + i] = (i == t) ? Bl[t] * Pl[t] : 0.f;
    }
    __syncthreads();

    if (tid < HD + T_) {
        float x[T_];
#pragma unroll
        for (int t = 0; t < T_; ++t) x[t] = X[t][tid];
#pragma unroll
        for (int t = 1; t < T_; ++t)
#pragma unroll
            for (int i = 0; i < t; ++i)
                x[t] -= L[t][i] * x[i];
        if (tid < HD) {
            float* Ug = Ubar + ((size_t)bh * NCHK + c) * (T_ * HD);
#pragma unroll
            for (int t = 0; t < T_; ++t) Ug[t * HD + tid] = x[t];
        } else {
            unsigned short* Wg = What + ((size_t)bh * NCHK + c) * (T_ * T_);
#pragma unroll
            for (int t = 0; t < T_; ++t) Wg[t * T_ + (tid - HD)] = f2bf(x[t]);
        }
    }

    unsigned short* Kg = KhatT + ((size_t)bh * NCHK + c) * (HD * T_);
    for (int idx = tid; idx < HD * T_; idx += 256) {
        int e = idx >> 5, t = idx & 31;
        float v = __expf(G[T_ - 1] - G[t]) * bf2f(Kb[(size_t)(tok0 + t) * TRIPLE + e]);
        Kg[idx] = f2bf(v);
    }
}

// Serial phase: 256 blocks = 32 bh x 8 d-slices of 16 rows.
__global__ __launch_bounds__(256) void chunk_scan(
    const unsigned short* __restrict__ qkvc, const float* __restrict__ gpre,
    const float* __restrict__ Ubar, const unsigned short* __restrict__ What,
    const unsigned short* __restrict__ Mhat, const unsigned short* __restrict__ KhatT,
    const float* __restrict__ Pbuf, unsigned short* __restrict__ og)
{
    __shared__ float          S  [16 * 132];
    __shared__ unsigned short Shi[16 * 136];
    __shared__ unsigned short Slo[16 * 136];
    __shared__ unsigned short CT [16 * 40];
    __shared__ unsigned short UT [16 * 40];

    const int blk = blockIdx.x;
    const int bh  = blk & 31;
    const int dsl = blk >> 5;
    const int b = bh >> 4, h = bh & 15;
    const int d0 = dsl * 16;
    const int tid = threadIdx.x;
    const int w = tid >> 6, lane = tid & 63;
    const int lr = lane & 15, lk8 = (lane >> 4) * 8, lrow4 = (lane >> 4) * 4;
    const int mt = w >> 1;
    const bool isQ = (w & 1);

    for (int i = tid; i < 16 * 132; i += 256) S[i] = 0.f;
    for (int i = tid; i < 16 * 136; i += 256) { Shi[i] = 0; Slo[i] = 0; }

    const size_t qbase = (size_t)b * N_ * TRIPLE;
    const unsigned short* Ab = qkvc + qbase + (isQ ? 0 : 2048) + h * HD;
    const float* gb = gpre + (size_t)b * N_ * INNER + h * HD;
    unsigned short* ogb = og + (size_t)b * N_ * INNER + h * HD;

    bf16x8 aF[4];
    bf16x8 wmF;
    float  sc4[4];
    float  g4[4];
    bf16x8 khF[2];
    float  gam;
    {
        const size_t cb = (size_t)bh * NCHK;
        const unsigned short* Am = Ab + (size_t)(mt * 16 + lr) * TRIPLE;
#pragma unroll
        for (int ks = 0; ks < 4; ++ks) aF[ks] = *(const bf16x8*)(Am + ks * 32 + lk8);
        if (!isQ) {
            wmF = *(const bf16x8*)(What + cb * (T_*T_) + (mt * 16 + lr) * T_ + lk8);
#pragma unroll
            for (int j = 0; j < 4; ++j)
                sc4[j] = Ubar[cb * (T_*HD) + (mt * 16 + lrow4 + j) * HD + d0 + lr];
        } else {
            wmF = *(const bf16x8*)(Mhat + cb * (T_*T_) + (mt * 16 + lr) * T_ + lk8);
#pragma unroll
            for (int j = 0; j < 4; ++j) {
                sc4[j] = Pbuf[cb * T_ + mt * 16 + lrow4 + j];
                g4[j]  = gb[(size_t)(mt * 16 + lrow4 + j) * INNER + d0 + lr];
            }
        }
#pragma unroll
        for (int j2 = 0; j2 < 2; ++j2)
            khF[j2] = *(const bf16x8*)(KhatT + cb * (HD*T_) + ((2*w + j2) * 16 + lr) * T_ + lk8);
        gam = Pbuf[cb * T_ + T_ - 1];
    }
    __syncthreads();

    for (int c = 0; c < NCHK; ++c) {
        const int np = (c + 1 < NCHK) ? c + 1 : c;
        const size_t cbn = (size_t)bh * NCHK + np;
        const int tok0n = np * T_;
        bf16x8 aFn[4], wmFn, khFn[2];
        float sc4n[4], g4n[4], gamn;
        {
            const unsigned short* Am = Ab + (size_t)(tok0n + mt * 16 + lr) * TRIPLE;
#pragma unroll
            for (int ks = 0; ks < 4; ++ks) aFn[ks] = *(const bf16x8*)(Am + ks * 32 + lk8);
            if (!isQ) {
                wmFn = *(const bf16x8*)(What + cbn * (T_*T_) + (mt * 16 + lr) * T_ + lk8);
#pragma unroll
                for (int j = 0; j < 4; ++j)
                    sc4n[j] = Ubar[cbn * (T_*HD) + (mt * 16 + lrow4 + j) * HD + d0 + lr];
            } else {
                wmFn = *(const bf16x8*)(Mhat + cbn * (T_*T_) + (mt * 16 + lr) * T_ + lk8);
#pragma unroll
                for (int j = 0; j < 4; ++j) {
                    sc4n[j] = Pbuf[cbn * T_ + mt * 16 + lrow4 + j];
                    g4n[j]  = gb[(size_t)(tok0n + mt * 16 + lrow4 + j) * INNER + d0 + lr];
                }
            }
#pragma unroll
            for (int j2 = 0; j2 < 2; ++j2)
                khFn[j2] = *(const bf16x8*)(KhatT + cbn * (HD*T_) + ((2*w + j2) * 16 + lr) * T_ + lk8);
            gamn = Pbuf[cbn * T_ + T_ - 1];
        }

        f32x4v accH = {0.f,0.f,0.f,0.f}, accL = {0.f,0.f,0.f,0.f};
#pragma unroll
        for (int ks = 0; ks < 4; ++ks) {
            bf16x8 hi = *(const bf16x8*)&Shi[lr * 136 + ks * 32 + lk8];
            bf16x8 lo = *(const bf16x8*)&Slo[lr * 136 + ks * 32 + lk8];
            accH = __builtin_amdgcn_mfma_f32_16x16x32_bf16(aF[ks], hi, accH, 0, 0, 0);
            accL = __builtin_amdgcn_mfma_f32_16x16x32_bf16(aF[ks], lo, accL, 0, 0, 0);
        }
        f32x4v accB;
#pragma unroll
        for (int j = 0; j < 4; ++j) accB[j] = accH[j] + accL[j];

        if (!isQ) {
            ushort4 cv;
            cv.x = f2bf(-accB[0]); cv.y = f2bf(-accB[1]);
            cv.z = f2bf(-accB[2]); cv.w = f2bf(-accB[3]);
            *(ushort4*)&CT[lr * 40 + mt * 16 + lrow4] = cv;
        }
        lds_barrier();

        if (!isQ) {
            f32x4v accU;
#pragma unroll
            for (int j = 0; j < 4; ++j) accU[j] = sc4[j];
            bf16x8 bC = *(const bf16x8*)&CT[lr * 40 + lk8];
            accU = __builtin_amdgcn_mfma_f32_16x16x32_bf16(wmF, bC, accU, 0, 0, 0);
            ushort4 uv;
            uv.x = f2bf(accU[0]); uv.y = f2bf(accU[1]);
            uv.z = f2bf(accU[2]); uv.w = f2bf(accU[3]);
            *(ushort4*)&UT[lr * 40 + mt * 16 + lrow4] = uv;
        }
        lds_barrier();

        bf16x8 utF = *(const bf16x8*)&UT[lr * 40 + lk8];

        if (isQ) {
            f32x4v accO;
#pragma unroll
            for (int j = 0; j < 4; ++j) accO[j] = sc4[j] * accB[j];
            accO = __builtin_amdgcn_mfma_f32_16x16x32_bf16(wmF, utF, accO, 0, 0, 0);
            const int tokb = c * T_ + mt * 16 + lrow4;
#pragma unroll
            for (int j = 0; j < 4; ++j)
                ogb[(size_t)(tokb + j) * INNER + d0 + lr] = f2bf(accO[j] * g4[j]);
        }

#pragma unroll
        for (int j2 = 0; j2 < 2; ++j2) {
            const int et = 2 * w + j2;
            f32x4v accS;
#pragma unroll
            for (int j = 0; j < 4; ++j)
                accS[j] = gam * S[(lrow4 + j) * 132 + et * 16 + lr];
            accS = __builtin_amdgcn_mfma_f32_16x16x32_bf16(utF, khF[j2], accS, 0, 0, 0);
#pragma unroll
            for (int j = 0; j < 4; ++j) {
                float v = accS[j];
                S[(lrow4 + j) * 132 + et * 16 + lr] = v;
                unsigned short hh = f2bf(v);
                Shi[(lrow4 + j) * 136 + et * 16 + lr] = hh;
                Slo[(lrow4 + j) * 136 + et * 16 + lr] = f2bf(v - bf2f(hh));
            }
        }
        lds_barrier();

#pragma unroll
        for (int ks = 0; ks < 4; ++ks) aF[ks] = aFn[ks];
        wmF = wmFn;
#pragma unroll
        for (int j = 0; j < 4; ++j) { sc4[j] = sc4n[j]; g4[j] = g4n[j]; }
        khF[0] = khFn[0]; khF[1] = khFn[1];
        gam = gamn;
    }
}

extern "C" void kernel_launch(void* const* d_in, const int* in_sizes, int n_in,
                              void* d_out, int out_size, void* d_ws, size_t ws_size,
                              hipStream_t stream) {
    const float* x      = (const float*)d_in[0];
    const float* W_qkv  = (const float*)d_in[1];
    const float* conv_w = (const float*)d_in[2];
    const float* W_ab   = (const float*)d_in[3];
    const float* b_ab   = (const float*)d_in[4];
    const float* W_g    = (const float*)d_in[5];
    const float* W_o    = (const float*)d_in[6];
    float* out = (float*)d_out;

    // Workspace layout. wqkvb | wgb | wob contiguous: fused GEMM uses
    // [wqkvb|wgb] as one 8192-row matrix; cast_all writes all three linearly.
    char* p = (char*)d_ws;
    unsigned short* wqkvb   = (unsigned short*)p; p += (size_t)TRIPLE * DM * 2;
    unsigned short* wgb     = (unsigned short*)p; p += (size_t)INNER * DM * 2;   // contiguous!
    unsigned short* wob     = (unsigned short*)p; p += (size_t)DM * INNER * 2;   // contiguous!
    unsigned short* wabhi   = (unsigned short*)p; p += (size_t)32 * DM * 2;
    unsigned short* wablo   = (unsigned short*)p; p += (size_t)32 * DM * 2;
    unsigned short* xb      = (unsigned short*)p; p += (size_t)M_ * DM * 2;
    unsigned short* xlo     = (unsigned short*)p; p += (size_t)M_ * DM * 2;
    unsigned short* qkv_pre = (unsigned short*)p; p += (size_t)M_ * TRIPLE * 2;
    unsigned short* qkv_c   = (unsigned short*)p; p += (size_t)M_ * TRIPLE * 2;
    float*          absig   = (float*)p;          p += (size_t)M_ * 32 * 4;
    float*          gpre    = (float*)p;          p += (size_t)M_ * INNER * 4;
    unsigned short* ogb     = (unsigned short*)p; p += (size_t)M_ * INNER * 2;
    (void)wgb;

    // chunk buffers overlay xb..qkv_pre (dead after gemm_ab / conv)
    char* q = (char*)xb;
    float*          Ubar  = (float*)q;          q += (size_t)32 * NCHK * T_ * HD * 4;
    unsigned short* KhatT = (unsigned short*)q; q += (size_t)32 * NCHK * HD * T_ * 2;
    unsigned short* What  = (unsigned short*)q; q += (size_t)32 * NCHK * T_ * T_ * 2;
    unsigned short* Mhat  = (unsigned short*)q; q += (size_t)32 * NCHK * T_ * T_ * 2;
    float*          Pbuf  = (float*)q;          q += (size_t)32 * NCHK * T_ * 4;

    dim3 blk(256);
    // one launch for ALL input casts (x hilo, fused weights, ab hilo)
    cast_all<<<dim3((NX_ + NW_ + NAB_) / 1024), blk, 0, stream>>>(
        x, W_qkv, W_g, W_o, W_ab, xb, xlo, wqkvb, wabhi, wablo);

    // fused: qkv (bf16) + g (fp32 silu) — 128^2 dbuf counted-vmcnt skeleton
    gemm_fused128<<<dim3((M_ / 128) * ((TRIPLE + INNER) / 128)), blk, 0, stream>>>(
        xb, wqkvb, qkv_pre, gpre, M_, TRIPLE, INNER, DM);
    // ab (split-bf16, fp32-grade) + sigmoid — K-split 4 ways, 256 blocks
    gemm_ab<<<dim3(M_ / 16), blk, 0, stream>>>(xb, xlo, wabhi, wablo, b_ab, absig);
    // conv + silu + l2norm (vectorized)
    conv_silu_norm<<<dim3(B_ * N_), blk, 0, stream>>>(qkv_pre, conv_w, qkv_c);

    chunk_prep<<<dim3(32 * NCHK), blk, 0, stream>>>(qkv_c, absig, Ubar, What, Mhat, KhatT, Pbuf);
    chunk_scan<<<dim3(256), blk, 0, stream>>>(qkv_c, gpre, Ubar, What, Mhat, KhatT, Pbuf, ogb);

    // W_o projection — 128^2-tile dbuf counted-vmcnt pipeline (2 blocks/CU)
    gemm_bf16f<<<dim3((M_ / 128) * (INNER / 128)), blk, 0, stream>>>(
        ogb, wob, out, M_, INNER, DM);
}

// Round 7
// 499.961 us; speedup vs baseline: 1.1701x; 1.1616x over previous
//
#include <hip/hip_runtime.h>
#include <math.h>
#include <stddef.h>

#define B_ 2
#define N_ 2048
#define DM 2048
#define H_ 16
#define HD 128
#define INNER 2048
#define TRIPLE 6144
#define M_ (B_ * N_)   // 4096
#define T_ 32          // chunk length
#define NCHK (N_ / T_) // 64 chunks

typedef __bf16 bf16x8 __attribute__((ext_vector_type(8)));
typedef float  f32x4v __attribute__((ext_vector_type(4)));
typedef __attribute__((address_space(1))) const void gvoid;
typedef __attribute__((address_space(3))) void lvoid;

__device__ __forceinline__ float sig_(float x) { return 1.0f / (1.0f + __expf(-x)); }

__device__ __forceinline__ unsigned short f2bf(float f) {
    unsigned u = __float_as_uint(f);
    u += 0x7FFFu + ((u >> 16) & 1u);     // RNE
    return (unsigned short)(u >> 16);
}
__device__ __forceinline__ float bf2f(unsigned short h) {
    return __uint_as_float((unsigned)h << 16);
}
__device__ __forceinline__ void unpack8(uint4 r, float* f) {
    f[0] = __uint_as_float(r.x << 16); f[1] = __uint_as_float(r.x & 0xffff0000u);
    f[2] = __uint_as_float(r.y << 16); f[3] = __uint_as_float(r.y & 0xffff0000u);
    f[4] = __uint_as_float(r.z << 16); f[5] = __uint_as_float(r.z & 0xffff0000u);
    f[6] = __uint_as_float(r.w << 16); f[7] = __uint_as_float(r.w & 0xffff0000u);
}

// Workgroup barrier that waits ONLY on LDS ops (lgkmcnt(0)); prefetched
// global loads stay in flight across it.
__device__ __forceinline__ void lds_barrier() {
    asm volatile("" ::: "memory");
    __builtin_amdgcn_s_waitcnt(0xC07F);
    __builtin_amdgcn_s_barrier();
    asm volatile("" ::: "memory");
}

// Raw barrier: NO waitcnt drain (counted-vmcnt pipeline crosses it).
__device__ __forceinline__ void bar() {
    asm volatile("" ::: "memory");
    __builtin_amdgcn_s_barrier();
    asm volatile("" ::: "memory");
}

// ============================================================================
// ONE launch for all input casts. Regions (4-elem granular):
//  [0, NX)            : x -> hi/lo split (xb, xlo)
//  [NX, NX+NW)        : [W_qkv | W_g | W_o] -> bf16 into contiguous wfused
//  [NX+NW, +NAB)      : W_ab -> hi/lo split (wabhi, wablo)
// ============================================================================
#define NX_ (M_ * DM)                       // 8,388,608
#define NW_ ((TRIPLE + 2 * INNER) * DM)     // 20,971,520
#define NAB_ (32 * DM)                      // 65,536
__global__ __launch_bounds__(256) void cast_all(
    const float* __restrict__ x, const float* __restrict__ Wq,
    const float* __restrict__ Wg, const float* __restrict__ Wo,
    const float* __restrict__ Wab,
    unsigned short* __restrict__ xb, unsigned short* __restrict__ xlo,
    unsigned short* __restrict__ wfused,
    unsigned short* __restrict__ wabhi, unsigned short* __restrict__ wablo)
{
    const int i = (blockIdx.x * 256 + threadIdx.x) * 4;
    if (i < NX_) {
        float4 v = *(const float4*)(x + i);
        ushort4 h, l;
        h.x = f2bf(v.x); l.x = f2bf(v.x - bf2f(h.x));
        h.y = f2bf(v.y); l.y = f2bf(v.y - bf2f(h.y));
        h.z = f2bf(v.z); l.z = f2bf(v.z - bf2f(h.z));
        h.w = f2bf(v.w); l.w = f2bf(v.w - bf2f(h.w));
        *(ushort4*)(xb + i)  = h;
        *(ushort4*)(xlo + i) = l;
    } else if (i < NX_ + NW_) {
        const int j = i - NX_;
        const float* s;
        if (j < TRIPLE * DM)                s = Wq + j;
        else if (j < (TRIPLE + INNER) * DM) s = Wg + (j - TRIPLE * DM);
        else                                s = Wo + (j - (TRIPLE + INNER) * DM);
        float4 v = *(const float4*)s;
        ushort4 u;
        u.x = f2bf(v.x); u.y = f2bf(v.y); u.z = f2bf(v.z); u.w = f2bf(v.w);
        *(ushort4*)(wfused + j) = u;
    } else if (i < NX_ + NW_ + NAB_) {
        const int j = i - NX_ - NW_;
        float4 v = *(const float4*)(Wab + j);
        ushort4 h, l;
        h.x = f2bf(v.x); l.x = f2bf(v.x - bf2f(h.x));
        h.y = f2bf(v.y); l.y = f2bf(v.y - bf2f(h.y));
        h.z = f2bf(v.z); l.z = f2bf(v.z - bf2f(h.z));
        h.w = f2bf(v.w); l.w = f2bf(v.w - bf2f(h.w));
        *(ushort4*)(wabhi + j) = h;
        *(ushort4*)(wablo + j) = l;
    }
}

// ============================================================================
// Fused (qkv | g) GEMM, 256x256-tile, merged-interval schedule.
// R7: VERBATIM revert to the R4/R2 loop — best measured 138.0 us (42.7%
// MfmaUtil). R6's 128^2 variant regressed (161us: FETCH 147->282 MB, tile
// reuse halved). Cycle ledger: MFMA ~2480 cyc/tile, LDS port ~2450 cyc/tile
// — both ~48% busy; further gain needs cross-wave LDS/MFMA overlap that 3
// schedule attempts failed to unlock. Banking this version.
// Race ledger: 4 bars/tile, staging slots P1:B0[kt+1] P2:A1[kt+1]
// P3:A0[kt+2] P4:B1[kt+2]; boundary vmcnt(4) after q11 issue; q10 (reg-only)
// after bar4 overlaps next-tile reads.
// ============================================================================
__global__ __launch_bounds__(512) void gemm_fused256(
    const unsigned short* __restrict__ A, const unsigned short* __restrict__ Bw,
    unsigned short* __restrict__ outQ, float* __restrict__ outG,
    int M, int NQ, int NG, int K)
{
    __shared__ unsigned short As[2][256 * 64];
    __shared__ unsigned short Bs[2][256 * 64];

    const int tid = threadIdx.x;
    const int w   = tid >> 6;       // 0..7
    const int l   = tid & 63;
    const int wm  = w >> 2;         // 0..1 (M)
    const int wn  = w & 3;          // 0..3 (N)
    const int lr  = l & 15;
    const int kg  = l >> 4;         // 0..3

    // XCD-aware bijective swizzle (512 blocks, 512 % 8 == 0)
    const int bid = blockIdx.x;
    const int swz = (bid & 7) * 64 + (bid >> 3);
    const int by  = swz & 15;       // 16 row-tiles
    const int bx  = swz >> 4;       // 32 col-tiles
    const int row0 = by * 256;
    const int col0 = bx * 256;

    // ---- staging addressing: LDS linear dest, pre-swizzled global source ----
    const int srow = w * 8 + (l >> 3);           // row within a 64-row load block
    const int schk = ((l & 7) ^ (l >> 3)) * 8;   // swizzled 8-elem chunk offset
    const unsigned short* Ath = A  + (size_t)(row0 + srow) * K + schk;
    const unsigned short* Bth = Bw + (size_t)(col0 + srow) * K + schk;

    // ---- fragment-read addressing (swizzled) ----
    const int fsw0 = ((0 + kg) ^ (lr & 7)) * 8;  // ks=0 chunk
    const int fsw1 = ((4 + kg) ^ (lr & 7)) * 8;  // ks=1 chunk
    const int arb  = wm * 64 + lr;               // + mh*128 + m*16
    const int brb  = wn * 32 + lr;               // + nh*128 + n*16

    f32x4v acc[2][2][4][2];                      // [mh][nh][m][n]
#pragma unroll
    for (int a0 = 0; a0 < 2; ++a0)
#pragma unroll
        for (int a1 = 0; a1 < 2; ++a1)
#pragma unroll
            for (int a2 = 0; a2 < 4; ++a2)
#pragma unroll
                for (int a3 = 0; a3 < 2; ++a3)
                    acc[a0][a1][a2][a3] = (f32x4v){0.f, 0.f, 0.f, 0.f};

#define STAGE_A(b, hb, kt) do {                                                  \
        const unsigned short* g_ = Ath + (size_t)((hb) * 128) * K + (kt) * 64;   \
        unsigned short* d_ = &As[b][((hb) * 128 + w * 8) * 64];                  \
        __builtin_amdgcn_global_load_lds((gvoid*)g_, (lvoid*)d_, 16, 0, 0);      \
        __builtin_amdgcn_global_load_lds((gvoid*)(g_ + (size_t)64 * K),          \
                                         (lvoid*)(d_ + 64 * 64), 16, 0, 0);      \
    } while (0)
#define STAGE_B(b, hb, kt) do {                                                  \
        const unsigned short* g_ = Bth + (size_t)((hb) * 128) * K + (kt) * 64;   \
        unsigned short* d_ = &Bs[b][((hb) * 128 + w * 8) * 64];                  \
        __builtin_amdgcn_global_load_lds((gvoid*)g_, (lvoid*)d_, 16, 0, 0);      \
        __builtin_amdgcn_global_load_lds((gvoid*)(g_ + (size_t)64 * K),          \
                                         (lvoid*)(d_ + 64 * 64), 16, 0, 0);      \
    } while (0)

#define RD_A(DST, BASE, HOFF)                                        \
    _Pragma("unroll")                                                \
    for (int m_ = 0; m_ < 4; ++m_) {                                 \
        const int r_ = ((HOFF) + arb + m_ * 16) * 64;                \
        DST[m_][0] = *(const bf16x8*)((BASE) + r_ + fsw0);           \
        DST[m_][1] = *(const bf16x8*)((BASE) + r_ + fsw1);           \
    }
#define RD_B(DST, BASE, HOFF)                                        \
    _Pragma("unroll")                                                \
    for (int n_ = 0; n_ < 2; ++n_) {                                 \
        const int r_ = ((HOFF) + brb + n_ * 16) * 64;                \
        DST[n_][0] = *(const bf16x8*)((BASE) + r_ + fsw0);           \
        DST[n_][1] = *(const bf16x8*)((BASE) + r_ + fsw1);           \
    }
#define Q_MFMA(MH, NH, AF, BF)                                               \
    __builtin_amdgcn_s_setprio(1);                                           \
    _Pragma("unroll")                                                        \
    for (int m_ = 0; m_ < 4; ++m_)                                           \
        _Pragma("unroll")                                                    \
        for (int n_ = 0; n_ < 2; ++n_) {                                     \
            acc[MH][NH][m_][n_] = __builtin_amdgcn_mfma_f32_16x16x32_bf16(   \
                AF[m_][0], BF[n_][0], acc[MH][NH][m_][n_], 0, 0, 0);         \
            acc[MH][NH][m_][n_] = __builtin_amdgcn_mfma_f32_16x16x32_bf16(   \
                AF[m_][1], BF[n_][1], acc[MH][NH][m_][n_], 0, 0, 0);         \
        }                                                                    \
    __builtin_amdgcn_s_setprio(0);

    const int KT = K >> 6;   // 32

    // Prologue: tile0 complete + A0/B1 of tile1 (12 loads); wait for tile0.
    STAGE_A(0, 0, 0); STAGE_B(0, 0, 0); STAGE_A(0, 1, 0); STAGE_B(0, 1, 0);
    STAGE_A(1, 0, 1); STAGE_B(1, 1, 1);
    asm volatile("s_waitcnt vmcnt(4)" ::: "memory");
    bar();

    bf16x8 aF[4][2];    // A0-half fragments (live I-A .. q01)
    bf16x8 aG[4][2];    // A1-half fragments (live I-C .. q10)
    bf16x8 bF0[2][2];   // B0-half (live I-A .. q10)
    bf16x8 bF1[2][2];   // B1-half (live I-B .. q11)

#pragma unroll 2
    for (int kt = 0; kt < KT; ++kt) {
        const unsigned short* Ab = As[kt & 1];
        const unsigned short* Bb = Bs[kt & 1];
        const int nb = (kt + 1) & 1;

        // ---- I-A: P1 reads (A0 both ks, B0 both ks) + stage B0[kt+1] ----
        RD_A(aF, Ab, 0);
        RD_B(bF0, Bb, 0);
        if (kt + 1 < KT) STAGE_B(nb, 0, kt + 1);
        bar();                                   // bar1

        // ---- I-B: q00 MFMA || P2 reads (B1) + stage A1[kt+1] ----
        Q_MFMA(0, 0, aF, bF0);
        RD_B(bF1, Bb, 128);
        if (kt + 1 < KT) STAGE_A(nb, 1, kt + 1);
        bar();                                   // bar2 (A0 reads done < here)

        // ---- I-C: q01 MFMA || P3 reads (A1) + stage A0[kt+2] ----
        Q_MFMA(0, 1, aF, bF1);
        RD_A(aG, Ab, 128);
        if (kt + 2 < KT) STAGE_A(kt & 1, 0, kt + 2);
        bar();                                   // bar3 (B1 reads done < here)

        // ---- I-D: q11 MFMA || stage B1[kt+2]; boundary; q10 after bar ----
        Q_MFMA(1, 1, aG, bF1);
        if (kt + 2 < KT) STAGE_B(kt & 1, 1, kt + 2);
        if (kt < KT - 2)       { asm volatile("s_waitcnt vmcnt(4)" ::: "memory"); }
        else if (kt == KT - 2) { asm volatile("s_waitcnt vmcnt(0)" ::: "memory"); }
        bar();                                   // bar4 (tile kt+1 visible)
        Q_MFMA(1, 0, aG, bF0);
        // next iteration's I-A reads (next buffer) overlap q10 execution
    }
#undef STAGE_A
#undef STAGE_B
#undef RD_A
#undef RD_B
#undef Q_MFMA

    // -------- epilogue --------
    const bool isG = (col0 >= NQ);   // block-uniform (NQ = 6144 = 24*256)
#pragma unroll
    for (int mh = 0; mh < 2; ++mh)
#pragma unroll
    for (int m = 0; m < 4; ++m) {
        const int rbase = row0 + mh * 128 + wm * 64 + m * 16 + kg * 4;
#pragma unroll
        for (int nh = 0; nh < 2; ++nh)
#pragma unroll
        for (int n = 0; n < 2; ++n) {
            const int c = col0 + nh * 128 + wn * 32 + n * 16 + lr;
#pragma unroll
            for (int j = 0; j < 4; ++j) {
                float v = acc[mh][nh][m][n][j];
                const size_t r = (size_t)(rbase + j);
                if (!isG) {
                    outQ[r * NQ + c] = f2bf(v);
                } else {
                    v = v * sig_(v);
                    outG[r * NG + (c - NQ)] = v;
                }
            }
        }
    }
}

// ============================================================================
// W_o projection GEMM (fp32 out): 128x128 tile, BK=64, double-buffered LDS
// (64 KiB -> 2 blocks/CU), counted vmcnt(8), 2 barriers/tile, XOR swizzle,
// XCD swizzle. (R4 kernel, unchanged.)
// ============================================================================
__global__ __launch_bounds__(256) void gemm_bf16f(
    const unsigned short* __restrict__ A, const unsigned short* __restrict__ Bw,
    float* __restrict__ C, int M, int N, int K)
{
    __shared__ unsigned short As[2][128 * 64];
    __shared__ unsigned short Bs[2][128 * 64];

    const int tid = threadIdx.x;
    const int w   = tid >> 6;      // 0..3
    const int l   = tid & 63;
    const int wm  = w >> 1;        // 0..1
    const int wn  = w & 1;         // 0..1
    const int lr  = l & 15;
    const int kg  = l >> 4;        // 0..3

    const int bid = blockIdx.x;
    const int swz = (bid & 7) * 64 + (bid >> 3);
    const int by  = swz & 31;      // 32 row-tiles (M=4096)
    const int bx  = swz >> 5;      // 16 col-tiles (N=2048)
    const int row0 = by * 128;
    const int col0 = bx * 128;

    const int srow = w * 8 + (l >> 3);           // 0..31
    const int schk = ((l & 7) ^ (l >> 3)) * 8;
    const unsigned short* Ath = A  + (size_t)(row0 + srow) * K + schk;
    const unsigned short* Bth = Bw + (size_t)(col0 + srow) * K + schk;

    const int fsw0 = ((0 + kg) ^ (lr & 7)) * 8;
    const int fsw1 = ((4 + kg) ^ (lr & 7)) * 8;
    const int arb  = wm * 64 + lr;
    const int brb  = wn * 64 + lr;

    f32x4v acc[4][4];
#pragma unroll
    for (int i = 0; i < 4; ++i)
#pragma unroll
        for (int j = 0; j < 4; ++j) acc[i][j] = (f32x4v){0.f, 0.f, 0.f, 0.f};

#define STAGE_T(buf, kt) do {                                                    \
        _Pragma("unroll")                                                        \
        for (int p_ = 0; p_ < 4; ++p_) {                                         \
            const unsigned short* ga_ = Ath + (size_t)(p_ * 32) * K + (kt) * 64; \
            const unsigned short* gb_ = Bth + (size_t)(p_ * 32) * K + (kt) * 64; \
            unsigned short* da_ = &As[buf][(p_ * 32 + w * 8) * 64];              \
            unsigned short* db_ = &Bs[buf][(p_ * 32 + w * 8) * 64];              \
            __builtin_amdgcn_global_load_lds((gvoid*)ga_, (lvoid*)da_, 16, 0, 0);\
            __builtin_amdgcn_global_load_lds((gvoid*)gb_, (lvoid*)db_, 16, 0, 0);\
        }                                                                        \
    } while (0)

    const int KT = K >> 6;   // 32

    STAGE_T(0, 0);
    STAGE_T(1, 1);
    asm volatile("s_waitcnt vmcnt(8)" ::: "memory");
    bar();

    bf16x8 aF[4][2], bF[4][2];

#pragma unroll 2
    for (int kt = 0; kt < KT; ++kt) {
        const unsigned short* Ab = As[kt & 1];
        const unsigned short* Bb = Bs[kt & 1];

#pragma unroll
        for (int m_ = 0; m_ < 4; ++m_) {
            const int r_ = (arb + m_ * 16) * 64;
            aF[m_][0] = *(const bf16x8*)(Ab + r_ + fsw0);
            aF[m_][1] = *(const bf16x8*)(Ab + r_ + fsw1);
        }
#pragma unroll
        for (int n_ = 0; n_ < 4; ++n_) {
            const int r_ = (brb + n_ * 16) * 64;
            bF[n_][0] = *(const bf16x8*)(Bb + r_ + fsw0);
            bF[n_][1] = *(const bf16x8*)(Bb + r_ + fsw1);
        }
        bar();                                    // all reads of buf cur done

        if (kt + 2 < KT) STAGE_T(kt & 1, kt + 2);

        __builtin_amdgcn_s_setprio(1);
#pragma unroll
        for (int ks = 0; ks < 2; ++ks)
#pragma unroll
            for (int m_ = 0; m_ < 4; ++m_)
#pragma unroll
                for (int n_ = 0; n_ < 4; ++n_)
                    acc[m_][n_] = __builtin_amdgcn_mfma_f32_16x16x32_bf16(
                        aF[m_][ks], bF[n_][ks], acc[m_][n_], 0, 0, 0);
        __builtin_amdgcn_s_setprio(0);

        if (kt < KT - 2) {
            asm volatile("s_waitcnt vmcnt(8)" ::: "memory");
        } else if (kt == KT - 2) {
            asm volatile("s_waitcnt vmcnt(0)" ::: "memory");
        }
        bar();
    }
#undef STAGE_T

#pragma unroll
    for (int m_ = 0; m_ < 4; ++m_)
#pragma unroll
        for (int j = 0; j < 4; ++j) {
            const int r = row0 + wm * 64 + m_ * 16 + kg * 4 + j;
#pragma unroll
            for (int n_ = 0; n_ < 4; ++n_) {
                const int c = col0 + wn * 64 + n_ * 16 + lr;
                C[(size_t)r * N + c] = acc[m_][n_][j];
            }
        }
}

// ab = sigmoid(x @ W_ab^T + b_ab) via split-bf16 MFMA (fp32-grade).
// 256 blocks x 16 rows; 4 waves split K 4-ways, LDS reduce.
__global__ __launch_bounds__(256) void gemm_ab(
    const unsigned short* __restrict__ xhi, const unsigned short* __restrict__ xlo,
    const unsigned short* __restrict__ wh, const unsigned short* __restrict__ wl,
    const float* __restrict__ b_ab, float* __restrict__ absig)
{
    __shared__ float sums[4][16][32];
    const int tid = threadIdx.x;
    const int w = tid >> 6, lane = tid & 63;
    const int lr = lane & 15, lk8 = (lane >> 4) * 8, lrow4 = (lane >> 4) * 4;
    const int row = blockIdx.x * 16 + lr;
    const int kw  = w * (DM / 4);    // per-wave K-chunk base

    f32x4v acc[2];
    acc[0] = (f32x4v){0.f,0.f,0.f,0.f};
    acc[1] = (f32x4v){0.f,0.f,0.f,0.f};
    const unsigned short* Ah = xhi + (size_t)row * DM + kw;
    const unsigned short* Al = xlo + (size_t)row * DM + kw;

    for (int k0 = 0; k0 < DM / 4; k0 += 32) {
        bf16x8 ah = *(const bf16x8*)(Ah + k0 + lk8);
        bf16x8 al = *(const bf16x8*)(Al + k0 + lk8);
#pragma unroll
        for (int nt = 0; nt < 2; ++nt) {
            bf16x8 whf = *(const bf16x8*)(wh + (size_t)(nt * 16 + lr) * DM + kw + k0 + lk8);
            bf16x8 wlf = *(const bf16x8*)(wl + (size_t)(nt * 16 + lr) * DM + kw + k0 + lk8);
            acc[nt] = __builtin_amdgcn_mfma_f32_16x16x32_bf16(ah, whf, acc[nt], 0, 0, 0);
            acc[nt] = __builtin_amdgcn_mfma_f32_16x16x32_bf16(ah, wlf, acc[nt], 0, 0, 0);
            acc[nt] = __builtin_amdgcn_mfma_f32_16x16x32_bf16(al, whf, acc[nt], 0, 0, 0);
        }
    }

#pragma unroll
    for (int nt = 0; nt < 2; ++nt)
#pragma unroll
        for (int j = 0; j < 4; ++j)
            sums[w][lrow4 + j][nt * 16 + lr] = acc[nt][j];
    __syncthreads();

    for (int e = tid; e < 512; e += 256) {
        const int r = e >> 5, c = e & 31;
        float s = sums[0][r][c] + sums[1][r][c] + sums[2][r][c] + sums[3][r][c];
        absig[(size_t)(blockIdx.x * 16 + r) * 32 + c] = sig_(s + b_ab[c]);
    }
}

// ============================================================================
// conv(K=4, causal, depthwise) + silu + per-head l2norm of q,k.
// R7: 4 tokens per block (1024 blocks). Old version read 4 token-rows per
// token (4x read amplification, ~200MB); now 7 rows serve 4 tokens (1.75x).
// v is written directly; q,k buffered in LDS fp32 for the norm pass.
// Norm reduction order changes (2-lane strided vs 8-lane strided) — fp32
// few-ulp effect, far below bf16 output quantization.
// ============================================================================
__global__ __launch_bounds__(256) void conv_silu_norm4(
    const unsigned short* __restrict__ qkv, const float* __restrict__ conv_w,
    unsigned short* __restrict__ outb)
{
    __shared__ float qk[4][32][132];    // [token][group][elem] (+4 pad)
    __shared__ float scales[4][32];
    const int blk = blockIdx.x;         // 1024 blocks
    const int t0g = blk * 4;            // first global token (bn)
    const int n0  = t0g & (N_ - 1);     // within-batch index (4 | N_, no straddle)
    const int tid = threadIdx.x;
    const unsigned short* base = qkv  + (size_t)t0g * TRIPLE;
    unsigned short*       ob   = outb + (size_t)t0g * TRIPLE;

#pragma unroll
    for (int it = 0; it < 3; ++it) {
        const int c8 = (tid + it * 256) * 8;
        float cw[32];
#pragma unroll
        for (int q4 = 0; q4 < 8; ++q4)
            *(float4*)&cw[q4 * 4] = *(const float4*)(conv_w + (size_t)c8 * 4 + q4 * 4);
        // 7 rows n0-3 .. n0+3 at this channel slice
        float xr[7][8];
#pragma unroll
        for (int j = 0; j < 7; ++j) {
            if (n0 - 3 + j >= 0) {
                uint4 r = *(const uint4*)(base + (ptrdiff_t)(j - 3) * TRIPLE + c8);
                unpack8(r, xr[j]);
            } else {
#pragma unroll
                for (int e = 0; e < 8; ++e) xr[j][e] = 0.f;
            }
        }
#pragma unroll
        for (int t = 0; t < 4; ++t) {
            float acc[8] = {0.f,0.f,0.f,0.f,0.f,0.f,0.f,0.f};
#pragma unroll
            for (int j = 0; j < 4; ++j)
#pragma unroll
                for (int e = 0; e < 8; ++e)
                    acc[e] += xr[t + j][e] * cw[e * 4 + j];
            float o[8];
#pragma unroll
            for (int e = 0; e < 8; ++e) o[e] = acc[e] * sig_(acc[e]);
            if (c8 < 4096) {
                // q or k: buffer fp32 for norm. group g = c8>>7, elem = c8&127
                float* dst = &qk[t][c8 >> 7][c8 & 127];
                *(float4*)(dst)     = *(float4*)&o[0];
                *(float4*)(dst + 4) = *(float4*)&o[4];
            } else {
                // v: no norm, store bf16 directly
                ushort4 u0, u1;
                u0.x = f2bf(o[0]); u0.y = f2bf(o[1]); u0.z = f2bf(o[2]); u0.w = f2bf(o[3]);
                u1.x = f2bf(o[4]); u1.y = f2bf(o[5]); u1.z = f2bf(o[6]); u1.w = f2bf(o[7]);
                *(ushort4*)(ob + (size_t)t * TRIPLE + c8)     = u0;
                *(ushort4*)(ob + (size_t)t * TRIPLE + c8 + 4) = u1;
            }
        }
    }
    __syncthreads();

    // norms: 128 (token,group) pairs; 2 threads per pair
    {
        const int pair = tid >> 1;      // 0..127
        const int half = tid & 1;
        const int t = pair >> 5;        // 0..3
        const int g = pair & 31;        // 0..31
        float s = 0.f;
        for (int i = half; i < HD; i += 2) { float v = qk[t][g][i]; s += v * v; }
        s += __shfl_xor(s, 1);
        if (half == 0) scales[t][g] = 1.0f / fmaxf(sqrtf(s), 1e-12f);
    }
    __syncthreads();

    // scaled q,k writeout: 4 tokens x 4096 channels
#pragma unroll
    for (int it = 0; it < 2; ++it) {
        const int c8 = (tid + it * 256) * 8;   // 0..4088
        const int g  = c8 >> 7;
        const float* src0 = &qk[0][g][c8 & 127];
#pragma unroll
        for (int t = 0; t < 4; ++t) {
            const float sc = scales[t][g];
            const float* s8 = src0 + t * (32 * 132);
            ushort4 u0, u1;
            u0.x = f2bf(s8[0] * sc); u0.y = f2bf(s8[1] * sc);
            u0.z = f2bf(s8[2] * sc); u0.w = f2bf(s8[3] * sc);
            u1.x = f2bf(s8[4] * sc); u1.y = f2bf(s8[5] * sc);
            u1.z = f2bf(s8[6] * sc); u1.w = f2bf(s8[7] * sc);
            *(ushort4*)(ob + (size_t)t * TRIPLE + c8)     = u0;
            *(ushort4*)(ob + (size_t)t * TRIPLE + c8 + 4) = u1;
        }
    }
}

// ---------------- chunked delta rule ----------------
__global__ __launch_bounds__(256) void chunk_prep(
    const unsigned short* __restrict__ qkvc, const float* __restrict__ absig,
    float* __restrict__ Ubar, unsigned short* __restrict__ What,
    unsigned short* __restrict__ Mhat, unsigned short* __restrict__ KhatT,
    float* __restrict__ Pbuf)
{
    __shared__ float G[T_], Pl[T_], Bl[T_];
    __shared__ float L[T_][T_ + 1];
    __shared__ float X[T_][161];
    const int bh = blockIdx.x >> 6;
    const int c  = blockIdx.x & 63;
    const int b  = bh >> 4;
    const int h  = bh & 15;
    const int tid = threadIdx.x;
    const int tok0 = c * T_;
    const size_t qbase = (size_t)b * N_ * TRIPLE;
    const unsigned short* Kb = qkvc + qbase + 2048 + h * HD;
    const unsigned short* Qb = qkvc + qbase + h * HD;
    const unsigned short* Vb = qkvc + qbase + 4096 + h * HD;
    const float* abb = absig + (size_t)b * N_ * 32;

    if (tid < T_) {
        G[tid]  = __logf(abb[(tok0 + tid) * 32 + h]);
        Bl[tid] = abb[(tok0 + tid) * 32 + 16 + h];
    }
    __syncthreads();
    if (tid == 0) {
        float run = 0.f;
        for (int t = 0; t < T_; ++t) { run += G[t]; G[t] = run; Pl[t] = __expf(run); }
    }
    __syncthreads();
    if (tid < T_) Pbuf[((size_t)bh * NCHK + c) * T_ + tid] = Pl[tid];

    const int w = tid >> 6, lane = tid & 63;
    const int lr = lane & 15, lk8 = (lane >> 4) * 8, lrow4 = (lane >> 4) * 4;
    const int mt = w >> 1, nt = w & 1;

    f32x4v akk = {0.f,0.f,0.f,0.f}, aqk = {0.f,0.f,0.f,0.f};
    const unsigned short* Km = Kb + (size_t)(tok0 + mt * 16 + lr) * TRIPLE;
    const unsigned short* Qm = Qb + (size_t)(tok0 + mt * 16 + lr) * TRIPLE;
    const unsigned short* Kn = Kb + (size_t)(tok0 + nt * 16 + lr) * TRIPLE;
#pragma unroll
    for (int ks = 0; ks < 4; ++ks) {
        bf16x8 aK = *(const bf16x8*)(Km + ks * 32 + lk8);
        bf16x8 aQ = *(const bf16x8*)(Qm + ks * 32 + lk8);
        bf16x8 bK = *(const bf16x8*)(Kn + ks * 32 + lk8);
        akk = __builtin_amdgcn_mfma_f32_16x16x32_bf16(aK, bK, akk, 0, 0, 0);
        aqk = __builtin_amdgcn_mfma_f32_16x16x32_bf16(aQ, bK, aqk, 0, 0, 0);
    }
    unsigned short* Mg = Mhat + ((size_t)bh * NCHK + c) * (T_ * T_);
#pragma unroll
    for (int reg = 0; reg < 4; ++reg) {
        int t = mt * 16 + lrow4 + reg;
        int i = nt * 16 + lr;
        float dec = __expf(G[t] - G[i]);
        L[t][i] = (i < t) ? Bl[t] * dec * akk[reg] : 0.f;
        Mg[t * T_ + i] = (i <= t) ? f2bf(dec * aqk[reg]) : (unsigned short)0;
    }
    __syncthreads();

    for (int idx = tid; idx < T_ * HD; idx += 256) {
        int t = idx >> 7, e = idx & 127;
        X[t][e] = Bl[t] * bf2f(Vb[(size_t)(tok0 + t) * TRIPLE + e]);
    }
    for (int idx = tid; idx < T_ * T_; idx += 256) {
        int t = idx >> 5, i = idx & 31;
        X[t][HD + i] = (i == t) ? Bl[t] * Pl[t] : 0.f;
    }
    __syncthreads();

    if (tid < HD + T_) {
        float x[T_];
#pragma unroll
        for (int t = 0; t < T_; ++t) x[t] = X[t][tid];
#pragma unroll
        for (int t = 1; t < T_; ++t)
#pragma unroll
            for (int i = 0; i < t; ++i)
                x[t] -= L[t][i] * x[i];
        if (tid < HD) {
            float* Ug = Ubar + ((size_t)bh * NCHK + c) * (T_ * HD);
#pragma unroll
            for (int t = 0; t < T_; ++t) Ug[t * HD + tid] = x[t];
        } else {
            unsigned short* Wg = What + ((size_t)bh * NCHK + c) * (T_ * T_);
#pragma unroll
            for (int t = 0; t < T_; ++t) Wg[t * T_ + (tid - HD)] = f2bf(x[t]);
        }
    }

    unsigned short* Kg = KhatT + ((size_t)bh * NCHK + c) * (HD * T_);
    for (int idx = tid; idx < HD * T_; idx += 256) {
        int e = idx >> 5, t = idx & 31;
        float v = __expf(G[T_ - 1] - G[t]) * bf2f(Kb[(size_t)(tok0 + t) * TRIPLE + e]);
        Kg[idx] = f2bf(v);
    }
}

// Serial phase: 256 blocks = 32 bh x 8 d-slices of 16 rows.
__global__ __launch_bounds__(256) void chunk_scan(
    const unsigned short* __restrict__ qkvc, const float* __restrict__ gpre,
    const float* __restrict__ Ubar, const unsigned short* __restrict__ What,
    const unsigned short* __restrict__ Mhat, const unsigned short* __restrict__ KhatT,
    const float* __restrict__ Pbuf, unsigned short* __restrict__ og)
{
    __shared__ float          S  [16 * 132];
    __shared__ unsigned short Shi[16 * 136];
    __shared__ unsigned short Slo[16 * 136];
    __shared__ unsigned short CT [16 * 40];
    __shared__ unsigned short UT [16 * 40];

    const int blk = blockIdx.x;
    const int bh  = blk & 31;
    const int dsl = blk >> 5;
    const int b = bh >> 4, h = bh & 15;
    const int d0 = dsl * 16;
    const int tid = threadIdx.x;
    const int w = tid >> 6, lane = tid & 63;
    const int lr = lane & 15, lk8 = (lane >> 4) * 8, lrow4 = (lane >> 4) * 4;
    const int mt = w >> 1;
    const bool isQ = (w & 1);

    for (int i = tid; i < 16 * 132; i += 256) S[i] = 0.f;
    for (int i = tid; i < 16 * 136; i += 256) { Shi[i] = 0; Slo[i] = 0; }

    const size_t qbase = (size_t)b * N_ * TRIPLE;
    const unsigned short* Ab = qkvc + qbase + (isQ ? 0 : 2048) + h * HD;
    const float* gb = gpre + (size_t)b * N_ * INNER + h * HD;
    unsigned short* ogb = og + (size_t)b * N_ * INNER + h * HD;

    bf16x8 aF[4];
    bf16x8 wmF;
    float  sc4[4];
    float  g4[4];
    bf16x8 khF[2];
    float  gam;
    {
        const size_t cb = (size_t)bh * NCHK;
        const unsigned short* Am = Ab + (size_t)(mt * 16 + lr) * TRIPLE;
#pragma unroll
        for (int ks = 0; ks < 4; ++ks) aF[ks] = *(const bf16x8*)(Am + ks * 32 + lk8);
        if (!isQ) {
            wmF = *(const bf16x8*)(What + cb * (T_*T_) + (mt * 16 + lr) * T_ + lk8);
#pragma unroll
            for (int j = 0; j < 4; ++j)
                sc4[j] = Ubar[cb * (T_*HD) + (mt * 16 + lrow4 + j) * HD + d0 + lr];
        } else {
            wmF = *(const bf16x8*)(Mhat + cb * (T_*T_) + (mt * 16 + lr) * T_ + lk8);
#pragma unroll
            for (int j = 0; j < 4; ++j) {
                sc4[j] = Pbuf[cb * T_ + mt * 16 + lrow4 + j];
                g4[j]  = gb[(size_t)(mt * 16 + lrow4 + j) * INNER + d0 + lr];
            }
        }
#pragma unroll
        for (int j2 = 0; j2 < 2; ++j2)
            khF[j2] = *(const bf16x8*)(KhatT + cb * (HD*T_) + ((2*w + j2) * 16 + lr) * T_ + lk8);
        gam = Pbuf[cb * T_ + T_ - 1];
    }
    __syncthreads();

    for (int c = 0; c < NCHK; ++c) {
        const int np = (c + 1 < NCHK) ? c + 1 : c;
        const size_t cbn = (size_t)bh * NCHK + np;
        const int tok0n = np * T_;
        bf16x8 aFn[4], wmFn, khFn[2];
        float sc4n[4], g4n[4], gamn;
        {
            const unsigned short* Am = Ab + (size_t)(tok0n + mt * 16 + lr) * TRIPLE;
#pragma unroll
            for (int ks = 0; ks < 4; ++ks) aFn[ks] = *(const bf16x8*)(Am + ks * 32 + lk8);
            if (!isQ) {
                wmFn = *(const bf16x8*)(What + cbn * (T_*T_) + (mt * 16 + lr) * T_ + lk8);
#pragma unroll
                for (int j = 0; j < 4; ++j)
                    sc4n[j] = Ubar[cbn * (T_*HD) + (mt * 16 + lrow4 + j) * HD + d0 + lr];
            } else {
                wmFn = *(const bf16x8*)(Mhat + cbn * (T_*T_) + (mt * 16 + lr) * T_ + lk8);
#pragma unroll
                for (int j = 0; j < 4; ++j) {
                    sc4n[j] = Pbuf[cbn * T_ + mt * 16 + lrow4 + j];
                    g4n[j]  = gb[(size_t)(tok0n + mt * 16 + lrow4 + j) * INNER + d0 + lr];
                }
            }
#pragma unroll
            for (int j2 = 0; j2 < 2; ++j2)
                khFn[j2] = *(const bf16x8*)(KhatT + cbn * (HD*T_) + ((2*w + j2) * 16 + lr) * T_ + lk8);
            gamn = Pbuf[cbn * T_ + T_ - 1];
        }

        f32x4v accH = {0.f,0.f,0.f,0.f}, accL = {0.f,0.f,0.f,0.f};
#pragma unroll
        for (int ks = 0; ks < 4; ++ks) {
            bf16x8 hi = *(const bf16x8*)&Shi[lr * 136 + ks * 32 + lk8];
            bf16x8 lo = *(const bf16x8*)&Slo[lr * 136 + ks * 32 + lk8];
            accH = __builtin_amdgcn_mfma_f32_16x16x32_bf16(aF[ks], hi, accH, 0, 0, 0);
            accL = __builtin_amdgcn_mfma_f32_16x16x32_bf16(aF[ks], lo, accL, 0, 0, 0);
        }
        f32x4v accB;
#pragma unroll
        for (int j = 0; j < 4; ++j) accB[j] = accH[j] + accL[j];

        if (!isQ) {
            ushort4 cv;
            cv.x = f2bf(-accB[0]); cv.y = f2bf(-accB[1]);
            cv.z = f2bf(-accB[2]); cv.w = f2bf(-accB[3]);
            *(ushort4*)&CT[lr * 40 + mt * 16 + lrow4] = cv;
        }
        lds_barrier();

        if (!isQ) {
            f32x4v accU;
#pragma unroll
            for (int j = 0; j < 4; ++j) accU[j] = sc4[j];
            bf16x8 bC = *(const bf16x8*)&CT[lr * 40 + lk8];
            accU = __builtin_amdgcn_mfma_f32_16x16x32_bf16(wmF, bC, accU, 0, 0, 0);
            ushort4 uv;
            uv.x = f2bf(accU[0]); uv.y = f2bf(accU[1]);
            uv.z = f2bf(accU[2]); uv.w = f2bf(accU[3]);
            *(ushort4*)&UT[lr * 40 + mt * 16 + lrow4] = uv;
        }
        lds_barrier();

        bf16x8 utF = *(const bf16x8*)&UT[lr * 40 + lk8];

        if (isQ) {
            f32x4v accO;
#pragma unroll
            for (int j = 0; j < 4; ++j) accO[j] = sc4[j] * accB[j];
            accO = __builtin_amdgcn_mfma_f32_16x16x32_bf16(wmF, utF, accO, 0, 0, 0);
            const int tokb = c * T_ + mt * 16 + lrow4;
#pragma unroll
            for (int j = 0; j < 4; ++j)
                ogb[(size_t)(tokb + j) * INNER + d0 + lr] = f2bf(accO[j] * g4[j]);
        }

#pragma unroll
        for (int j2 = 0; j2 < 2; ++j2) {
            const int et = 2 * w + j2;
            f32x4v accS;
#pragma unroll
            for (int j = 0; j < 4; ++j)
                accS[j] = gam * S[(lrow4 + j) * 132 + et * 16 + lr];
            accS = __builtin_amdgcn_mfma_f32_16x16x32_bf16(utF, khF[j2], accS, 0, 0, 0);
#pragma unroll
            for (int j = 0; j < 4; ++j) {
                float v = accS[j];
                S[(lrow4 + j) * 132 + et * 16 + lr] = v;
                unsigned short hh = f2bf(v);
                Shi[(lrow4 + j) * 136 + et * 16 + lr] = hh;
                Slo[(lrow4 + j) * 136 + et * 16 + lr] = f2bf(v - bf2f(hh));
            }
        }
        lds_barrier();

#pragma unroll
        for (int ks = 0; ks < 4; ++ks) aF[ks] = aFn[ks];
        wmF = wmFn;
#pragma unroll
        for (int j = 0; j < 4; ++j) { sc4[j] = sc4n[j]; g4[j] = g4n[j]; }
        khF[0] = khFn[0]; khF[1] = khFn[1];
        gam = gamn;
    }
}

extern "C" void kernel_launch(void* const* d_in, const int* in_sizes, int n_in,
                              void* d_out, int out_size, void* d_ws, size_t ws_size,
                              hipStream_t stream) {
    const float* x      = (const float*)d_in[0];
    const float* W_qkv  = (const float*)d_in[1];
    const float* conv_w = (const float*)d_in[2];
    const float* W_ab   = (const float*)d_in[3];
    const float* b_ab   = (const float*)d_in[4];
    const float* W_g    = (const float*)d_in[5];
    const float* W_o    = (const float*)d_in[6];
    float* out = (float*)d_out;

    // Workspace layout. wqkvb | wgb | wob contiguous: fused GEMM uses
    // [wqkvb|wgb] as one 8192-row matrix; cast_all writes all three linearly.
    char* p = (char*)d_ws;
    unsigned short* wqkvb   = (unsigned short*)p; p += (size_t)TRIPLE * DM * 2;
    unsigned short* wgb     = (unsigned short*)p; p += (size_t)INNER * DM * 2;   // contiguous!
    unsigned short* wob     = (unsigned short*)p; p += (size_t)DM * INNER * 2;   // contiguous!
    unsigned short* wabhi   = (unsigned short*)p; p += (size_t)32 * DM * 2;
    unsigned short* wablo   = (unsigned short*)p; p += (size_t)32 * DM * 2;
    unsigned short* xb      = (unsigned short*)p; p += (size_t)M_ * DM * 2;
    unsigned short* xlo     = (unsigned short*)p; p += (size_t)M_ * DM * 2;
    unsigned short* qkv_pre = (unsigned short*)p; p += (size_t)M_ * TRIPLE * 2;
    unsigned short* qkv_c   = (unsigned short*)p; p += (size_t)M_ * TRIPLE * 2;
    float*          absig   = (float*)p;          p += (size_t)M_ * 32 * 4;
    float*          gpre    = (float*)p;          p += (size_t)M_ * INNER * 4;
    unsigned short* ogb     = (unsigned short*)p; p += (size_t)M_ * INNER * 2;
    (void)wgb;

    // chunk buffers overlay xb..qkv_pre (dead after gemm_ab / conv)
    char* q = (char*)xb;
    float*          Ubar  = (float*)q;          q += (size_t)32 * NCHK * T_ * HD * 4;
    unsigned short* KhatT = (unsigned short*)q; q += (size_t)32 * NCHK * HD * T_ * 2;
    unsigned short* What  = (unsigned short*)q; q += (size_t)32 * NCHK * T_ * T_ * 2;
    unsigned short* Mhat  = (unsigned short*)q; q += (size_t)32 * NCHK * T_ * T_ * 2;
    float*          Pbuf  = (float*)q;          q += (size_t)32 * NCHK * T_ * 4;

    dim3 blk(256);
    // one launch for ALL input casts (x hilo, fused weights, ab hilo)
    cast_all<<<dim3((NX_ + NW_ + NAB_) / 1024), blk, 0, stream>>>(
        x, W_qkv, W_g, W_o, W_ab, xb, xlo, wqkvb, wabhi, wablo);

    // fused: qkv (bf16) + g (fp32 silu) — R4 merged-interval 256x256 schedule
    gemm_fused256<<<dim3(((TRIPLE + INNER) / 256) * (M_ / 256)), dim3(512), 0, stream>>>(
        xb, wqkvb, qkv_pre, gpre, M_, TRIPLE, INNER, DM);
    // ab (split-bf16, fp32-grade) + sigmoid — K-split 4 ways, 256 blocks
    gemm_ab<<<dim3(M_ / 16), blk, 0, stream>>>(xb, xlo, wabhi, wablo, b_ab, absig);
    // conv + silu + l2norm — 4 tokens/block (1.75x read amp vs 4x)
    conv_silu_norm4<<<dim3(M_ / 4), blk, 0, stream>>>(qkv_pre, conv_w, qkv_c);

    chunk_prep<<<dim3(32 * NCHK), blk, 0, stream>>>(qkv_c, absig, Ubar, What, Mhat, KhatT, Pbuf);
    chunk_scan<<<dim3(256), blk, 0, stream>>>(qkv_c, gpre, Ubar, What, Mhat, KhatT, Pbuf, ogb);

    // W_o projection — 128^2-tile dbuf counted-vmcnt pipeline (2 blocks/CU)
    gemm_bf16f<<<dim3((M_ / 128) * (INNER / 128)), blk, 0, stream>>>(
        ogb, wob, out, M_, INNER, DM);
}